// Round 1
// baseline (359.199 us; speedup 1.0000x reference)
//
#include <hip/hip_runtime.h>

// Problem constants
#define NB 2
#define NN 1024
#define ND 1024
#define NH 16
#define DH 64
#define SCALE2 0.015625f   // (64^-0.5)^2
#define LNEPS 1e-5f

typedef _Float16 f16x8 __attribute__((ext_vector_type(8)));
typedef _Float16 f16x4 __attribute__((ext_vector_type(4)));
typedef float f32x4 __attribute__((ext_vector_type(4)));

// ---------------- helpers ----------------
__device__ inline void gload_lds16(const void* g, void* l) {
    __builtin_amdgcn_global_load_lds(
        (const __attribute__((address_space(1))) void*)g,
        (__attribute__((address_space(3))) void*)l, 16, 0, 0);
}

// ---------------- fp32 -> f16 pack ----------------
__global__ __launch_bounds__(256) void pack_f16(const float* __restrict__ src,
                                                _Float16* __restrict__ dst, int n) {
    int i = (blockIdx.x * 256 + threadIdx.x) * 4;
    if (i >= n) return;
    f32x4 v = *(const f32x4*)&src[i];
    f16x4 h = __builtin_convertvector(v, f16x4);
    *(f16x4*)&dst[i] = h;
}

// ---------------- fp32 (R x C) -> f16 transposed (C x R) ----------------
__global__ __launch_bounds__(256) void transpose_f2h(const float* __restrict__ src,
                                                     _Float16* __restrict__ dst,
                                                     int R, int C) {
    __shared__ float tile[32][33];
    int c0 = blockIdx.x * 32, r0 = blockIdx.y * 32;
    int tx = threadIdx.x, ty = threadIdx.y;   // block (32,8)
#pragma unroll
    for (int i = 0; i < 4; ++i)
        tile[ty + 8 * i][tx] = src[(size_t)(r0 + ty + 8 * i) * C + c0 + tx];
    __syncthreads();
#pragma unroll
    for (int i = 0; i < 4; ++i)
        dst[(size_t)(c0 + ty + 8 * i) * R + r0 + tx] = (_Float16)tile[tx][ty + 8 * i];
}

// ---------------- f16 MFMA GEMM:  C(MxN) = A(MxK) @ BT(NxK)^T ----------------
// 128x128 tile, BK=32, 4 waves, double-buffered LDS via global_load_lds(16B).
#define BM 128
#define BN 128
#define BK 32
__global__ __launch_bounds__(256) void gemm_bt(const _Float16* __restrict__ A,
                                               const _Float16* __restrict__ BT,
                                               float* __restrict__ Cf,
                                               _Float16* __restrict__ Ch,
                                               int M, int N, int K,
                                               size_t sA, size_t sB, size_t sC) {
    A += (size_t)blockIdx.z * sA;
    BT += (size_t)blockIdx.z * sB;

    __shared__ _Float16 Asm[2][BM * BK];
    __shared__ _Float16 Bsm[2][BN * BK];

    const int tid = threadIdx.x;
    const int lane = tid & 63;
    const int w = tid >> 6;
    const int wr = w >> 1, wc = w & 1;
    const int brow = blockIdx.y * BM;
    const int bcol = blockIdx.x * BN;
    const int g = lane >> 4, r = lane & 15;

    f32x4 acc[4][4];
#pragma unroll
    for (int m = 0; m < 4; ++m)
#pragma unroll
        for (int n = 0; n < 4; ++n) acc[m][n] = (f32x4){0.f, 0.f, 0.f, 0.f};

    const int nk = K / BK;

    // prologue: stage tile 0 into buffer 0
#pragma unroll
    for (int it2 = 0; it2 < 2; ++it2) {
        int o = (it2 * 256 + tid) * 16;     // byte offset in 8192B tile
        int row = o >> 6;                   // 64 B per row (32 f16)
        int cb = o & 63;
        gload_lds16((const char*)(A + (size_t)(brow + row) * K) + cb, (char*)Asm[0] + o);
        gload_lds16((const char*)(BT + (size_t)(bcol + row) * K) + cb, (char*)Bsm[0] + o);
    }
    __syncthreads();

    int cur = 0;
    for (int kt = 0; kt < nk; ++kt) {
        if (kt + 1 < nk) {
            int kof = (kt + 1) * BK;
#pragma unroll
            for (int it2 = 0; it2 < 2; ++it2) {
                int o = (it2 * 256 + tid) * 16;
                int row = o >> 6;
                int cb = o & 63;
                gload_lds16((const char*)(A + (size_t)(brow + row) * K + kof) + cb,
                            (char*)Asm[cur ^ 1] + o);
                gload_lds16((const char*)(BT + (size_t)(bcol + row) * K + kof) + cb,
                            (char*)Bsm[cur ^ 1] + o);
            }
        }
        f16x8 af[4], bf[4];
#pragma unroll
        for (int m = 0; m < 4; ++m)
            af[m] = *(const f16x8*)&Asm[cur][(64 * wr + 16 * m + r) * BK + 8 * g];
#pragma unroll
        for (int n = 0; n < 4; ++n)
            bf[n] = *(const f16x8*)&Bsm[cur][(64 * wc + 16 * n + r) * BK + 8 * g];
#pragma unroll
        for (int m = 0; m < 4; ++m)
#pragma unroll
            for (int n = 0; n < 4; ++n)
                acc[m][n] = __builtin_amdgcn_mfma_f32_16x16x32_f16(af[m], bf[n], acc[m][n], 0, 0, 0);
        __syncthreads();   // drains vmcnt: next buffer staged; cur free to overwrite
        cur ^= 1;
    }

    // epilogue: C/D layout col = lane&15, row = (lane>>4)*4 + reg   [m89-verified]
    if (Cf) {
        float* C = Cf + (size_t)blockIdx.z * sC;
#pragma unroll
        for (int m = 0; m < 4; ++m)
#pragma unroll
            for (int n = 0; n < 4; ++n) {
                int col = bcol + 64 * wc + 16 * n + r;
#pragma unroll
                for (int r4 = 0; r4 < 4; ++r4) {
                    int row = brow + 64 * wr + 16 * m + 4 * g + r4;
                    C[(size_t)row * N + col] = acc[m][n][r4];
                }
            }
    }
    if (Ch) {
        _Float16* C = Ch + (size_t)blockIdx.z * sC;
#pragma unroll
        for (int m = 0; m < 4; ++m)
#pragma unroll
            for (int n = 0; n < 4; ++n) {
                int col = bcol + 64 * wc + 16 * n + r;
#pragma unroll
                for (int r4 = 0; r4 < 4; ++r4) {
                    int row = brow + 64 * wr + 16 * m + 4 * g + r4;
                    C[(size_t)row * N + col] = (_Float16)acc[m][n][r4];
                }
            }
    }
}

// ---------------- flash attention over (b,h): softmax(SCALE2 * QK @ k^T) @ v ----------------
// fp32 VALU, 64x64 tiles, 4x4 register micro-tiles, online softmax.
__global__ __launch_bounds__(256) void flash_kernel(const float* __restrict__ QK,
                                                    const float* __restrict__ Kf,
                                                    const float* __restrict__ Vf,
                                                    float* __restrict__ Opre) {
    __shared__ float Qs[64][68], Ks[64][68], Vs[64][68], Ps[64][68];
    const int tid = threadIdx.x;
    const int tx = tid & 15, ty = tid >> 4;
    const int it = blockIdx.x;          // 0..15 (i-tile)
    const int bh = blockIdx.y;          // 0..31
    const int b = bh >> 4, h = bh & 15;

    const float* QKb = QK + ((size_t)b * NN + it * 64) * ND + h * 64;
    const float* Kb = Kf + (size_t)b * NN * ND + h * 64;
    const float* Vb = Vf + (size_t)b * NN * ND + h * 64;

    // stage Q tile (64 rows x 64 cols)
    {
        int rr = tid >> 2, q4 = tid & 3;
#pragma unroll
        for (int u = 0; u < 4; ++u) {
            int c = q4 * 16 + u * 4;
            *(f32x4*)&Qs[rr][c] = *(const f32x4*)&QKb[(size_t)rr * ND + c];
        }
    }

    float m_i[4], l_i[4];
    f32x4 o[4];
#pragma unroll
    for (int i = 0; i < 4; ++i) { m_i[i] = -1e30f; l_i[i] = 0.f; o[i] = (f32x4){0.f,0.f,0.f,0.f}; }

    for (int jt = 0; jt < 16; ++jt) {
        __syncthreads();   // protect Ks/Vs/Ps from previous iteration readers
        {
            int rr = tid >> 2, q4 = tid & 3;
#pragma unroll
            for (int u = 0; u < 4; ++u) {
                int c = q4 * 16 + u * 4;
                *(f32x4*)&Ks[rr][c] = *(const f32x4*)&Kb[(size_t)(jt * 64 + rr) * ND + c];
                *(f32x4*)&Vs[rr][c] = *(const f32x4*)&Vb[(size_t)(jt * 64 + rr) * ND + c];
            }
        }
        __syncthreads();

        // S[i][j] over rows ty+16i, cols tx+16j
        float S[4][4] = {};
#pragma unroll 4
        for (int e4 = 0; e4 < 16; ++e4) {
            f32x4 qv[4], kv[4];
#pragma unroll
            for (int i = 0; i < 4; ++i) qv[i] = *(const f32x4*)&Qs[ty + 16 * i][e4 * 4];
#pragma unroll
            for (int j = 0; j < 4; ++j) kv[j] = *(const f32x4*)&Ks[tx + 16 * j][e4 * 4];
#pragma unroll
            for (int i = 0; i < 4; ++i)
#pragma unroll
                for (int j = 0; j < 4; ++j)
                    S[i][j] += qv[i].x * kv[j].x + qv[i].y * kv[j].y +
                               qv[i].z * kv[j].z + qv[i].w * kv[j].w;
        }

        // online softmax per row (16 tx threads per row)
#pragma unroll
        for (int i = 0; i < 4; ++i) {
            float mx = -1e30f;
#pragma unroll
            for (int j = 0; j < 4; ++j) { S[i][j] *= SCALE2; mx = fmaxf(mx, S[i][j]); }
            mx = fmaxf(mx, __shfl_xor(mx, 1));
            mx = fmaxf(mx, __shfl_xor(mx, 2));
            mx = fmaxf(mx, __shfl_xor(mx, 4));
            mx = fmaxf(mx, __shfl_xor(mx, 8));
            float mnew = fmaxf(m_i[i], mx);
            float corr = __expf(m_i[i] - mnew);
            m_i[i] = mnew;
            float rs = 0.f;
#pragma unroll
            for (int j = 0; j < 4; ++j) {
                float p = __expf(S[i][j] - mnew);
                Ps[ty + 16 * i][tx + 16 * j] = p;
                rs += p;
            }
            rs += __shfl_xor(rs, 1);
            rs += __shfl_xor(rs, 2);
            rs += __shfl_xor(rs, 4);
            rs += __shfl_xor(rs, 8);
            l_i[i] = l_i[i] * corr + rs;
            o[i] *= corr;
        }
        __syncthreads();   // Ps visible to all

        // PV: o[i] (cols 4tx..4tx+3) += P[row] @ V
#pragma unroll
        for (int i = 0; i < 4; ++i) {
            const float* prow = &Ps[ty + 16 * i][0];
            f32x4 acc = o[i];
#pragma unroll 4
            for (int j4 = 0; j4 < 16; ++j4) {
                f32x4 p4 = *(const f32x4*)&prow[j4 * 4];
                acc += p4.x * (*(const f32x4*)&Vs[j4 * 4 + 0][tx * 4]);
                acc += p4.y * (*(const f32x4*)&Vs[j4 * 4 + 1][tx * 4]);
                acc += p4.z * (*(const f32x4*)&Vs[j4 * 4 + 2][tx * 4]);
                acc += p4.w * (*(const f32x4*)&Vs[j4 * 4 + 3][tx * 4]);
            }
            o[i] = acc;
        }
    }

    float* Ob = Opre + ((size_t)b * NN + it * 64) * ND + h * 64;
#pragma unroll
    for (int i = 0; i < 4; ++i) {
        f32x4 res = o[i] * (1.0f / l_i[i]);
        *(f32x4*)&Ob[(size_t)(ty + 16 * i) * ND + tx * 4] = res;
    }
}

// ---------------- residual + LayerNorm ----------------
__global__ __launch_bounds__(256) void ln_kernel(const float* __restrict__ Opre,
                                                 const float* __restrict__ Y,
                                                 const float* __restrict__ gamma,
                                                 const float* __restrict__ beta,
                                                 float* __restrict__ Out) {
    const int row = blockIdx.x;   // 0..2047
    const int t = threadIdx.x;
    const float* op = Opre + (size_t)row * ND;
    const float* yp = Y + (size_t)row * ND;
    f32x4 z = *(const f32x4*)&op[t * 4] + *(const f32x4*)&yp[t * 4];

    __shared__ float red[8];
    float s = z.x + z.y + z.z + z.w;
#pragma unroll
    for (int off = 32; off; off >>= 1) s += __shfl_xor(s, off);
    if ((t & 63) == 0) red[t >> 6] = s;
    __syncthreads();
    float mean = (red[0] + red[1] + red[2] + red[3]) * (1.0f / 1024.0f);

    f32x4 d = z - mean;
    float sq = d.x * d.x + d.y * d.y + d.z * d.z + d.w * d.w;
#pragma unroll
    for (int off = 32; off; off >>= 1) sq += __shfl_xor(sq, off);
    if ((t & 63) == 0) red[4 + (t >> 6)] = sq;
    __syncthreads();
    float var = (red[4] + red[5] + red[6] + red[7]) * (1.0f / 1024.0f);
    float rstd = rsqrtf(var + LNEPS);

    f32x4 gg = *(const f32x4*)&gamma[t * 4];
    f32x4 bb = *(const f32x4*)&beta[t * 4];
    f32x4 res = d * rstd * gg + bb;
    *(f32x4*)&Out[(size_t)row * ND + t * 4] = res;
}

// ---------------- launch ----------------
extern "C" void kernel_launch(void* const* d_in, const int* in_sizes, int n_in,
                              void* d_out, int out_size, void* d_ws, size_t ws_size,
                              hipStream_t stream) {
    const float* x = (const float*)d_in[0];
    const float* y = (const float*)d_in[1];
    const float* Wq = (const float*)d_in[2];
    const float* Wk = (const float*)d_in[3];
    const float* Wv = (const float*)d_in[4];
    const float* gamma = (const float*)d_in[5];
    const float* beta = (const float*)d_in[6];
    float* out = (float*)d_out;

    const size_t MB = 1024ull * 1024ull;
    char* w = (char*)d_ws;
    _Float16* xh  = (_Float16*)(w + 0 * MB);    // 4 MB  (2M f16)
    _Float16* yh  = (_Float16*)(w + 4 * MB);    // 4 MB
    _Float16* WqT = (_Float16*)(w + 8 * MB);    // 2 MB
    _Float16* WkT = (_Float16*)(w + 10 * MB);   // 2 MB
    _Float16* WvT = (_Float16*)(w + 12 * MB);   // 2 MB
    _Float16* qh  = (_Float16*)(w + 14 * MB);   // 4 MB
    _Float16* kTh = (_Float16*)(w + 18 * MB);   // 4 MB
    float* kf32   = (float*)(w + 22 * MB);      // 8 MB
    float* vf32   = (float*)(w + 30 * MB);      // 8 MB
    float* QK32   = (float*)(w + 38 * MB);      // 8 MB
    float* outpre = (float*)(w + 46 * MB);      // 8 MB   (total 54 MB)

    const int NEL = NB * NN * ND;  // 2M

    pack_f16<<<NEL / 1024, 256, 0, stream>>>(x, xh, NEL);
    pack_f16<<<NEL / 1024, 256, 0, stream>>>(y, yh, NEL);

    dim3 tb(32, 8);
    transpose_f2h<<<dim3(32, 32), tb, 0, stream>>>(Wq, WqT, 1024, 1024);
    transpose_f2h<<<dim3(32, 32), tb, 0, stream>>>(Wk, WkT, 1024, 1024);
    transpose_f2h<<<dim3(32, 32), tb, 0, stream>>>(Wv, WvT, 1024, 1024);

    // q = x@Wq (f16 out), kflat = y@Wk (f32), vflat = y@Wv (f32)
    gemm_bt<<<dim3(8, 16, 1), 256, 0, stream>>>(xh, WqT, nullptr, qh, 2048, 1024, 1024, 0, 0, 0);
    gemm_bt<<<dim3(8, 16, 1), 256, 0, stream>>>(yh, WkT, kf32, nullptr, 2048, 1024, 1024, 0, 0, 0);
    gemm_bt<<<dim3(8, 16, 1), 256, 0, stream>>>(yh, WvT, vf32, nullptr, 2048, 1024, 1024, 0, 0, 0);

    // kTh[b] = kflat[b]^T  (f16)
    transpose_f2h<<<dim3(32, 32), tb, 0, stream>>>(kf32, kTh, 1024, 1024);
    transpose_f2h<<<dim3(32, 32), tb, 0, stream>>>(kf32 + NN * ND, kTh + NN * ND, 1024, 1024);

    // QK[b] = q[b] @ kflat[b]   (f32 out)
    gemm_bt<<<dim3(8, 8, 2), 256, 0, stream>>>(qh, kTh, QK32, nullptr, 1024, 1024, 1024,
                                               (size_t)NN * ND, (size_t)NN * ND, (size_t)NN * ND);

    // flash attention + epilogue LN
    flash_kernel<<<dim3(16, 32), 256, 0, stream>>>(QK32, kf32, vf32, outpre);
    ln_kernel<<<NB * NN, 256, 0, stream>>>(outpre, y, gamma, beta, out);
}

// Round 2
// 191.041 us; speedup vs baseline: 1.8802x; 1.8802x over previous
//
#include <hip/hip_runtime.h>

// Problem constants
#define NB 2
#define NN 1024
#define ND 1024
#define NH 16
#define DH 64
#define SCALE2 0.015625f   // (64^-0.5)^2
#define LNEPS 1e-5f

typedef _Float16 f16x8 __attribute__((ext_vector_type(8)));
typedef _Float16 f16x4 __attribute__((ext_vector_type(4)));
typedef float f32x4 __attribute__((ext_vector_type(4)));

// ---------------- helpers ----------------
__device__ inline void gload_lds16(const void* g, void* l) {
    __builtin_amdgcn_global_load_lds(
        (const __attribute__((address_space(1))) void*)g,
        (__attribute__((address_space(3))) void*)l, 16, 0, 0);
}

// ---------------- fp32 -> f16 pack ----------------
__global__ __launch_bounds__(256) void pack_f16(const float* __restrict__ src,
                                                _Float16* __restrict__ dst, int n) {
    int i = (blockIdx.x * 256 + threadIdx.x) * 4;
    if (i >= n) return;
    f32x4 v = *(const f32x4*)&src[i];
    f16x4 h = __builtin_convertvector(v, f16x4);
    *(f16x4*)&dst[i] = h;
}

// ---------------- fp32 (R x C) -> f16 transposed (C x R) ----------------
__global__ __launch_bounds__(256) void transpose_f2h(const float* __restrict__ src,
                                                     _Float16* __restrict__ dst,
                                                     int R, int C) {
    __shared__ float tile[32][33];
    int c0 = blockIdx.x * 32, r0 = blockIdx.y * 32;
    int tx = threadIdx.x, ty = threadIdx.y;   // block (32,8)
#pragma unroll
    for (int i = 0; i < 4; ++i)
        tile[ty + 8 * i][tx] = src[(size_t)(r0 + ty + 8 * i) * C + c0 + tx];
    __syncthreads();
#pragma unroll
    for (int i = 0; i < 4; ++i)
        dst[(size_t)(c0 + ty + 8 * i) * R + r0 + tx] = (_Float16)tile[tx][ty + 8 * i];
}

// ---------------- f16 MFMA GEMM:  C(MxN) = A(MxK) @ BT(NxK)^T ----------------
// 128x128 tile, BK=32, 4 waves, double-buffered LDS via global_load_lds(16B).
#define BM 128
#define BN 128
#define BK 32
__global__ __launch_bounds__(256) void gemm_bt(const _Float16* __restrict__ A,
                                               const _Float16* __restrict__ BT,
                                               float* __restrict__ Cf,
                                               _Float16* __restrict__ Ch,
                                               int M, int N, int K,
                                               size_t sA, size_t sB, size_t sC) {
    A += (size_t)blockIdx.z * sA;
    BT += (size_t)blockIdx.z * sB;

    __shared__ _Float16 Asm[2][BM * BK];
    __shared__ _Float16 Bsm[2][BN * BK];

    const int tid = threadIdx.x;
    const int lane = tid & 63;
    const int w = tid >> 6;
    const int wr = w >> 1, wc = w & 1;
    const int brow = blockIdx.y * BM;
    const int bcol = blockIdx.x * BN;
    const int g = lane >> 4, r = lane & 15;

    f32x4 acc[4][4];
#pragma unroll
    for (int m = 0; m < 4; ++m)
#pragma unroll
        for (int n = 0; n < 4; ++n) acc[m][n] = (f32x4){0.f, 0.f, 0.f, 0.f};

    const int nk = K / BK;

    // prologue: stage tile 0 into buffer 0
#pragma unroll
    for (int it2 = 0; it2 < 2; ++it2) {
        int o = (it2 * 256 + tid) * 16;     // byte offset in 8192B tile
        int row = o >> 6;                   // 64 B per row (32 f16)
        int cb = o & 63;
        gload_lds16((const char*)(A + (size_t)(brow + row) * K) + cb, (char*)Asm[0] + o);
        gload_lds16((const char*)(BT + (size_t)(bcol + row) * K) + cb, (char*)Bsm[0] + o);
    }
    __syncthreads();

    int cur = 0;
    for (int kt = 0; kt < nk; ++kt) {
        if (kt + 1 < nk) {
            int kof = (kt + 1) * BK;
#pragma unroll
            for (int it2 = 0; it2 < 2; ++it2) {
                int o = (it2 * 256 + tid) * 16;
                int row = o >> 6;
                int cb = o & 63;
                gload_lds16((const char*)(A + (size_t)(brow + row) * K + kof) + cb,
                            (char*)Asm[cur ^ 1] + o);
                gload_lds16((const char*)(BT + (size_t)(bcol + row) * K + kof) + cb,
                            (char*)Bsm[cur ^ 1] + o);
            }
        }
        f16x8 af[4], bf[4];
#pragma unroll
        for (int m = 0; m < 4; ++m)
            af[m] = *(const f16x8*)&Asm[cur][(64 * wr + 16 * m + r) * BK + 8 * g];
#pragma unroll
        for (int n = 0; n < 4; ++n)
            bf[n] = *(const f16x8*)&Bsm[cur][(64 * wc + 16 * n + r) * BK + 8 * g];
#pragma unroll
        for (int m = 0; m < 4; ++m)
#pragma unroll
            for (int n = 0; n < 4; ++n)
                acc[m][n] = __builtin_amdgcn_mfma_f32_16x16x32_f16(af[m], bf[n], acc[m][n], 0, 0, 0);
        __syncthreads();   // drains vmcnt: next buffer staged; cur free to overwrite
        cur ^= 1;
    }

    // epilogue: C/D layout col = lane&15, row = (lane>>4)*4 + reg   [m89-verified]
    if (Cf) {
        float* C = Cf + (size_t)blockIdx.z * sC;
#pragma unroll
        for (int m = 0; m < 4; ++m)
#pragma unroll
            for (int n = 0; n < 4; ++n) {
                int col = bcol + 64 * wc + 16 * n + r;
#pragma unroll
                for (int r4 = 0; r4 < 4; ++r4) {
                    int row = brow + 64 * wr + 16 * m + 4 * g + r4;
                    C[(size_t)row * N + col] = acc[m][n][r4];
                }
            }
    }
    if (Ch) {
        _Float16* C = Ch + (size_t)blockIdx.z * sC;
#pragma unroll
        for (int m = 0; m < 4; ++m)
#pragma unroll
            for (int n = 0; n < 4; ++n) {
                int col = bcol + 64 * wc + 16 * n + r;
#pragma unroll
                for (int r4 = 0; r4 < 4; ++r4) {
                    int row = brow + 64 * wr + 16 * m + 4 * g + r4;
                    C[(size_t)row * N + col] = (_Float16)acc[m][n][r4];
                }
            }
    }
}

// ---------------- MFMA flash attention over (b,h) ----------------
// 4 waves/block, each wave owns 16 Q-rows of a 64-row i-tile.
// S = Q'K^T via mfma 16x16x32 f16; softmax in D-fragment registers
// (row = 4g+reg, 16-lane shfl_xor row-reduce); P relayout via wave-private
// LDS slab (stride 72 f16 = 144B -> 16B-aligned ds_read_b128, bank-spread).
// NO __syncthreads anywhere: K/V fragments read straight from global (L2-hot),
// so the compiler can pipeline loads across the jt loop.
__global__ __launch_bounds__(256) void flash_mfma(const _Float16* __restrict__ Qh,
                                                  const _Float16* __restrict__ Kh,
                                                  const _Float16* __restrict__ VTh,
                                                  float* __restrict__ Opre) {
    __shared__ _Float16 Ps[4][16][72];
    const int tid = threadIdx.x;
    const int lane = tid & 63;
    const int w = tid >> 6;
    const int g = lane >> 4, r = lane & 15;
    const int it = blockIdx.x;          // 0..15 (i-tile)
    const int bh = blockIdx.y;          // 0..31
    const int b = bh >> 4, h = bh & 15;

    const _Float16* Qb = Qh + ((size_t)b * NN + it * 64 + 16 * w) * ND + h * 64;
    const _Float16* Kb = Kh + (size_t)b * NN * ND + h * 64;
    const _Float16* Vb = VTh + ((size_t)b * ND + h * 64) * NN;   // [dh][kv], row stride NN

    // Q A-fragments: row = lane&15 (within wave's 16 rows), cols kk*32+8g..+7
    f16x8 qa[2];
#pragma unroll
    for (int kk = 0; kk < 2; ++kk)
        qa[kk] = *(const f16x8*)&Qb[(size_t)r * ND + kk * 32 + 8 * g];

    float m_i[4], l_i[4];
    f32x4 o[4];
#pragma unroll
    for (int i = 0; i < 4; ++i) { m_i[i] = -1e30f; l_i[i] = 0.f; o[i] = (f32x4){0.f,0.f,0.f,0.f}; }

    for (int jt = 0; jt < 16; ++jt) {
        // ---- S tile: 4 col-frags x 2 k-steps ----
        f32x4 s[4];
#pragma unroll
        for (int f = 0; f < 4; ++f) s[f] = (f32x4){0.f, 0.f, 0.f, 0.f};
#pragma unroll
        for (int f = 0; f < 4; ++f)
#pragma unroll
            for (int kk = 0; kk < 2; ++kk) {
                f16x8 kb = *(const f16x8*)&Kb[(size_t)(jt * 64 + 16 * f + r) * ND + kk * 32 + 8 * g];
                s[f] = __builtin_amdgcn_mfma_f32_16x16x32_f16(qa[kk], kb, s[f], 0, 0, 0);
            }
#pragma unroll
        for (int f = 0; f < 4; ++f) s[f] *= SCALE2;

        // ---- online softmax: D layout row = 4g+reg, col = 16f+r ----
        float corr[4];
#pragma unroll
        for (int reg = 0; reg < 4; ++reg) {
            float mx = fmaxf(fmaxf(s[0][reg], s[1][reg]), fmaxf(s[2][reg], s[3][reg]));
            mx = fmaxf(mx, __shfl_xor(mx, 1));
            mx = fmaxf(mx, __shfl_xor(mx, 2));
            mx = fmaxf(mx, __shfl_xor(mx, 4));
            mx = fmaxf(mx, __shfl_xor(mx, 8));
            float mnew = fmaxf(m_i[reg], mx);
            corr[reg] = __expf(m_i[reg] - mnew);
            m_i[reg] = mnew;
            float rs = 0.f;
#pragma unroll
            for (int f = 0; f < 4; ++f) {
                float p = __expf(s[f][reg] - mnew);
                Ps[w][4 * g + reg][16 * f + r] = (_Float16)p;
                rs += p;
            }
            rs += __shfl_xor(rs, 1);
            rs += __shfl_xor(rs, 2);
            rs += __shfl_xor(rs, 4);
            rs += __shfl_xor(rs, 8);
            l_i[reg] = l_i[reg] * corr[reg] + rs;
        }
#pragma unroll
        for (int n = 0; n < 4; ++n)
#pragma unroll
            for (int reg = 0; reg < 4; ++reg) o[n][reg] *= corr[reg];

        // ---- P A-fragments from wave-private LDS (ordered by lgkmcnt, no barrier) ----
        f16x8 pa[2];
#pragma unroll
        for (int kk = 0; kk < 2; ++kk)
            pa[kk] = *(const f16x8*)&Ps[w][r][kk * 32 + 8 * g];

        // ---- PV: O += P @ V, B-frags straight from V^T global ----
#pragma unroll
        for (int n = 0; n < 4; ++n)
#pragma unroll
            for (int kk = 0; kk < 2; ++kk) {
                f16x8 vb = *(const f16x8*)&Vb[(size_t)(16 * n + r) * NN + jt * 64 + kk * 32 + 8 * g];
                o[n] = __builtin_amdgcn_mfma_f32_16x16x32_f16(pa[kk], vb, o[n], 0, 0, 0);
            }
    }

    float* Ob = Opre + ((size_t)b * NN + it * 64 + 16 * w) * ND + h * 64;
#pragma unroll
    for (int reg = 0; reg < 4; ++reg) {
        float inv = 1.0f / l_i[reg];
#pragma unroll
        for (int n = 0; n < 4; ++n)
            Ob[(size_t)(4 * g + reg) * ND + 16 * n + r] = o[n][reg] * inv;
    }
}

// ---------------- residual + LayerNorm ----------------
__global__ __launch_bounds__(256) void ln_kernel(const float* __restrict__ Opre,
                                                 const float* __restrict__ Y,
                                                 const float* __restrict__ gamma,
                                                 const float* __restrict__ beta,
                                                 float* __restrict__ Out) {
    const int row = blockIdx.x;   // 0..2047
    const int t = threadIdx.x;
    const float* op = Opre + (size_t)row * ND;
    const float* yp = Y + (size_t)row * ND;
    f32x4 z = *(const f32x4*)&op[t * 4] + *(const f32x4*)&yp[t * 4];

    __shared__ float red[8];
    float s = z.x + z.y + z.z + z.w;
#pragma unroll
    for (int off = 32; off; off >>= 1) s += __shfl_xor(s, off);
    if ((t & 63) == 0) red[t >> 6] = s;
    __syncthreads();
    float mean = (red[0] + red[1] + red[2] + red[3]) * (1.0f / 1024.0f);

    f32x4 d = z - mean;
    float sq = d.x * d.x + d.y * d.y + d.z * d.z + d.w * d.w;
#pragma unroll
    for (int off = 32; off; off >>= 1) sq += __shfl_xor(sq, off);
    if ((t & 63) == 0) red[4 + (t >> 6)] = sq;
    __syncthreads();
    float var = (red[4] + red[5] + red[6] + red[7]) * (1.0f / 1024.0f);
    float rstd = rsqrtf(var + LNEPS);

    f32x4 gg = *(const f32x4*)&gamma[t * 4];
    f32x4 bb = *(const f32x4*)&beta[t * 4];
    f32x4 res = d * rstd * gg + bb;
    *(f32x4*)&Out[(size_t)row * ND + t * 4] = res;
}

// ---------------- launch ----------------
extern "C" void kernel_launch(void* const* d_in, const int* in_sizes, int n_in,
                              void* d_out, int out_size, void* d_ws, size_t ws_size,
                              hipStream_t stream) {
    const float* x = (const float*)d_in[0];
    const float* y = (const float*)d_in[1];
    const float* Wq = (const float*)d_in[2];
    const float* Wk = (const float*)d_in[3];
    const float* Wv = (const float*)d_in[4];
    const float* gamma = (const float*)d_in[5];
    const float* beta = (const float*)d_in[6];
    float* out = (float*)d_out;

    const size_t MB = 1024ull * 1024ull;
    char* w = (char*)d_ws;
    _Float16* xh  = (_Float16*)(w + 0 * MB);    // 4 MB  (freed after q GEMM)
    _Float16* QKh = (_Float16*)(w + 0 * MB);    // 4 MB  (overlays xh)
    _Float16* yh  = (_Float16*)(w + 4 * MB);    // 4 MB
    _Float16* WqT = (_Float16*)(w + 8 * MB);    // 2 MB
    _Float16* WkT = (_Float16*)(w + 10 * MB);   // 2 MB
    _Float16* WvT = (_Float16*)(w + 12 * MB);   // 2 MB
    _Float16* qh  = (_Float16*)(w + 14 * MB);   // 4 MB
    _Float16* kTh = (_Float16*)(w + 18 * MB);   // 4 MB
    float* kf32   = (float*)(w + 22 * MB);      // 8 MB
    float* vf32   = (float*)(w + 30 * MB);      // 8 MB
    _Float16* khf = (_Float16*)(w + 38 * MB);   // 4 MB
    _Float16* vTh = (_Float16*)(w + 42 * MB);   // 4 MB
    float* outpre = (float*)(w + 46 * MB);      // 8 MB   (total 54 MB)

    const int NEL = NB * NN * ND;  // 2M

    pack_f16<<<NEL / 1024, 256, 0, stream>>>(x, xh, NEL);
    pack_f16<<<NEL / 1024, 256, 0, stream>>>(y, yh, NEL);

    dim3 tb(32, 8);
    transpose_f2h<<<dim3(32, 32), tb, 0, stream>>>(Wq, WqT, 1024, 1024);
    transpose_f2h<<<dim3(32, 32), tb, 0, stream>>>(Wk, WkT, 1024, 1024);
    transpose_f2h<<<dim3(32, 32), tb, 0, stream>>>(Wv, WvT, 1024, 1024);

    // q = x@Wq (f16), kflat = y@Wk (f32 + f16), vflat = y@Wv (f32)
    gemm_bt<<<dim3(8, 16, 1), 256, 0, stream>>>(xh, WqT, nullptr, qh, 2048, 1024, 1024, 0, 0, 0);
    gemm_bt<<<dim3(8, 16, 1), 256, 0, stream>>>(yh, WkT, kf32, khf, 2048, 1024, 1024, 0, 0, 0);
    gemm_bt<<<dim3(8, 16, 1), 256, 0, stream>>>(yh, WvT, vf32, nullptr, 2048, 1024, 1024, 0, 0, 0);

    // kTh[b] = kflat[b]^T (f16) for the QK GEMM; vTh[b] = vflat[b]^T (f16) for flash PV
    transpose_f2h<<<dim3(32, 32), tb, 0, stream>>>(kf32, kTh, 1024, 1024);
    transpose_f2h<<<dim3(32, 32), tb, 0, stream>>>(kf32 + NN * ND, kTh + NN * ND, 1024, 1024);
    transpose_f2h<<<dim3(32, 32), tb, 0, stream>>>(vf32, vTh, 1024, 1024);
    transpose_f2h<<<dim3(32, 32), tb, 0, stream>>>(vf32 + NN * ND, vTh + NN * ND, 1024, 1024);

    // QK[b] = q[b] @ kflat[b]   (f16 out, direct to flash's Q operand)
    gemm_bt<<<dim3(8, 8, 2), 256, 0, stream>>>(qh, kTh, nullptr, QKh, 1024, 1024, 1024,
                                               (size_t)NN * ND, (size_t)NN * ND, (size_t)NN * ND);

    // MFMA flash attention + epilogue LN
    flash_mfma<<<dim3(16, 32), 256, 0, stream>>>(QKh, khf, vTh, outpre);
    ln_kernel<<<NB * NN, 256, 0, stream>>>(outpre, y, gamma, beta, out);
}

// Round 3
// 133.855 us; speedup vs baseline: 2.6835x; 1.4272x over previous
//
#include <hip/hip_runtime.h>

// Problem constants
#define NB 2
#define NN 1024
#define ND 1024
#define NH 16
#define SCALE2 0.015625f   // (64^-0.5)^2
#define LNEPS 1e-5f
#define BK 32

typedef _Float16 f16x8 __attribute__((ext_vector_type(8)));
typedef _Float16 f16x4 __attribute__((ext_vector_type(4)));
typedef float f32x4 __attribute__((ext_vector_type(4)));

// ---------------- helpers ----------------
__device__ inline void gload_lds16(const void* g, void* l) {
    __builtin_amdgcn_global_load_lds(
        (const __attribute__((address_space(1))) void*)g,
        (__attribute__((address_space(3))) void*)l, 16, 0, 0);
}

// ---------------- fp32 -> f16 pack ----------------
__global__ __launch_bounds__(256) void pack_f16(const float* __restrict__ src,
                                                _Float16* __restrict__ dst, int n) {
    int i = (blockIdx.x * 256 + threadIdx.x) * 4;
    if (i >= n) return;
    f32x4 v = *(const f32x4*)&src[i];
    f16x4 h = __builtin_convertvector(v, f16x4);
    *(f16x4*)&dst[i] = h;
}

// ---------------- fp32 (R x C) -> f16 transposed (C x R) ----------------
__global__ __launch_bounds__(256) void transpose_f2h(const float* __restrict__ src,
                                                     _Float16* __restrict__ dst,
                                                     int R, int C) {
    __shared__ float tile[32][33];
    int c0 = blockIdx.x * 32, r0 = blockIdx.y * 32;
    int tx = threadIdx.x, ty = threadIdx.y;   // block (32,8)
#pragma unroll
    for (int i = 0; i < 4; ++i)
        tile[ty + 8 * i][tx] = src[(size_t)(r0 + ty + 8 * i) * C + c0 + tx];
    __syncthreads();
#pragma unroll
    for (int i = 0; i < 4; ++i)
        dst[(size_t)(c0 + ty + 8 * i) * R + r0 + tx] = (_Float16)tile[tx][ty + 8 * i];
}

// ---------------- templated f16 MFMA GEMM body: C(MxN) = A @ BT^T ----------------
// 4 waves as 2x2, wave tile (BM/2)x(BN/2). Double-buffered LDS via global_load_lds(16B).
template <int BM, int BN>
__device__ __forceinline__ void gemm_body(const _Float16* __restrict__ A,
                                          const _Float16* __restrict__ BT,
                                          _Float16* __restrict__ C,
                                          int lda, int ldb, int ldc,
                                          int brow, int bcol, int K) {
    __shared__ _Float16 Asm[2][BM * BK];
    __shared__ _Float16 Bsm[2][BN * BK];
    constexpr int MR = BM / 32;                 // A-frags per wave
    constexpr int NC = BN / 32;                 // B-frags per wave
    constexpr int ABYTES = BM * BK * 2;
    constexpr int NLOAD = (BM + BN) * BK * 2 / 4096;
    static_assert(ABYTES % 4096 == 0, "A region must align to load passes");

    const int tid = threadIdx.x;
    const int lane = tid & 63;
    const int w = tid >> 6;
    const int wr = w >> 1, wc = w & 1;
    const int g = lane >> 4, r = lane & 15;

    f32x4 acc[MR][NC];
#pragma unroll
    for (int m = 0; m < MR; ++m)
#pragma unroll
        for (int n = 0; n < NC; ++n) acc[m][n] = (f32x4){0.f, 0.f, 0.f, 0.f};

    auto stage = [&](int buf, int kof) {
#pragma unroll
        for (int itl = 0; itl < NLOAD; ++itl) {
            int o = itl * 4096 + tid * 16;
            if (o < ABYTES) {
                int row = o >> 6, cb = o & 63;
                gload_lds16((const char*)(A + (size_t)(brow + row) * lda + kof) + cb,
                            (char*)Asm[buf] + o);
            } else {
                int o2 = o - ABYTES;
                int row = o2 >> 6, cb = o2 & 63;
                gload_lds16((const char*)(BT + (size_t)(bcol + row) * ldb + kof) + cb,
                            (char*)Bsm[buf] + o2);
            }
        }
    };

    stage(0, 0);
    __syncthreads();

    int cur = 0;
    const int nk = K / BK;
    for (int kt = 0; kt < nk; ++kt) {
        if (kt + 1 < nk) stage(cur ^ 1, (kt + 1) * BK);
        f16x8 af[MR], bf[NC];
#pragma unroll
        for (int m = 0; m < MR; ++m)
            af[m] = *(const f16x8*)&Asm[cur][((BM / 2) * wr + 16 * m + r) * BK + 8 * g];
#pragma unroll
        for (int n = 0; n < NC; ++n)
            bf[n] = *(const f16x8*)&Bsm[cur][((BN / 2) * wc + 16 * n + r) * BK + 8 * g];
#pragma unroll
        for (int m = 0; m < MR; ++m)
#pragma unroll
            for (int n = 0; n < NC; ++n)
                acc[m][n] = __builtin_amdgcn_mfma_f32_16x16x32_f16(af[m], bf[n], acc[m][n], 0, 0, 0);
        __syncthreads();   // next buffer staged; cur free to overwrite
        cur ^= 1;
    }

    // epilogue: C/D layout col = lane&15, row = (lane>>4)*4 + reg   [m89-verified]
#pragma unroll
    for (int m = 0; m < MR; ++m)
#pragma unroll
        for (int n = 0; n < NC; ++n) {
            int col = bcol + (BN / 2) * wc + 16 * n + r;
#pragma unroll
            for (int r4 = 0; r4 < 4; ++r4) {
                int row = brow + (BM / 2) * wr + 16 * m + 4 * g + r4;
                C[(size_t)row * ldc + col] = (_Float16)acc[m][n][r4];
            }
        }
}

// ---------------- fused QKV(+transposed) GEMM: 4 segments, 1024 blocks ----------------
// seg0: qh  = xh @ Wq          (2048x1024)
// seg1: khf = yh @ Wk          (2048x1024)
// seg2: kT  = WkT @ yh^T       (1024x2048, = k transposed, ldc 2048)
// seg3: vT  = WvT @ yh^T       (1024x2048, = v transposed, ldc 2048)
__global__ __launch_bounds__(256) void gemm_qkv(const _Float16* __restrict__ xh,
                                                const _Float16* __restrict__ yh,
                                                const _Float16* __restrict__ WqT,
                                                const _Float16* __restrict__ WkT,
                                                const _Float16* __restrict__ WvT,
                                                _Float16* __restrict__ qh,
                                                _Float16* __restrict__ khf,
                                                _Float16* __restrict__ kT,
                                                _Float16* __restrict__ vT) {
    const int seg = blockIdx.x >> 8;
    const int t = blockIdx.x & 255;
    const _Float16 *A, *BT;
    _Float16* C;
    int ldc, brow, bcol;
    if (seg == 0)      { A = xh;  BT = WqT; C = qh;  ldc = 1024; brow = (t >> 4) * 128; bcol = (t & 15) * 64; }
    else if (seg == 1) { A = yh;  BT = WkT; C = khf; ldc = 1024; brow = (t >> 4) * 128; bcol = (t & 15) * 64; }
    else if (seg == 2) { A = WkT; BT = yh;  C = kT;  ldc = 2048; brow = (t >> 5) * 128; bcol = (t & 31) * 64; }
    else               { A = WvT; BT = yh;  C = vT;  ldc = 2048; brow = (t >> 5) * 128; bcol = (t & 31) * 64; }
    gemm_body<128, 64>(A, BT, C, 1024, 1024, ldc, brow, bcol, 1024);
}

// ---------------- batched QK GEMM: QK[b] = q[b] @ kflat[b] (BT = kT slice) ----------------
__global__ __launch_bounds__(256) void gemm_qk(const _Float16* __restrict__ qh,
                                               const _Float16* __restrict__ kT,
                                               _Float16* __restrict__ QKh) {
    const int z = blockIdx.z;
    gemm_body<64, 64>(qh + (size_t)z * NN * ND, kT + z * NN, QKh + (size_t)z * NN * ND,
                      1024, 2048, 1024, blockIdx.y * 64, blockIdx.x * 64, 1024);
}

// ---------------- MFMA flash attention over (b,h), register-pipelined ----------------
// 4 waves/block, each wave owns 16 Q-rows. K(jt+1) and V(jt) fragments prefetched
// into registers so global latency hides under S-MFMA + softmax. No __syncthreads.
__global__ __launch_bounds__(256) void flash_mfma(const _Float16* __restrict__ Qh,
                                                  const _Float16* __restrict__ Kh,
                                                  const _Float16* __restrict__ VT,
                                                  float* __restrict__ Opre) {
    __shared__ _Float16 Ps[4][16][72];
    const int tid = threadIdx.x;
    const int lane = tid & 63;
    const int w = tid >> 6;
    const int g = lane >> 4, r = lane & 15;
    const int it = blockIdx.x;          // 0..15 (i-tile)
    const int bh = blockIdx.y;          // 0..31
    const int b = bh >> 4, h = bh & 15;

    const _Float16* Qb = Qh + ((size_t)b * NN + it * 64 + 16 * w) * ND + h * 64;
    const _Float16* Kb = Kh + (size_t)b * NN * ND + h * 64;
    const _Float16* Vb = VT + (size_t)(h * 64) * (NB * NN) + b * NN;   // ld = 2048

    // Q A-fragments
    f16x8 qa[2];
#pragma unroll
    for (int kk = 0; kk < 2; ++kk)
        qa[kk] = *(const f16x8*)&Qb[(size_t)r * ND + kk * 32 + 8 * g];

    // K fragments for jt=0
    f16x8 kc[4][2];
#pragma unroll
    for (int f = 0; f < 4; ++f)
#pragma unroll
        for (int kk = 0; kk < 2; ++kk)
            kc[f][kk] = *(const f16x8*)&Kb[(size_t)(16 * f + r) * ND + kk * 32 + 8 * g];

    float m_i[4], l_i[4];
    f32x4 o[4];
#pragma unroll
    for (int i = 0; i < 4; ++i) { m_i[i] = -1e30f; l_i[i] = 0.f; o[i] = (f32x4){0.f,0.f,0.f,0.f}; }

    for (int jt = 0; jt < 16; ++jt) {
        // ---- prefetch next-tile K and this-tile V into registers (hide under compute) ----
        f16x8 kn[4][2];
        if (jt < 15) {
#pragma unroll
            for (int f = 0; f < 4; ++f)
#pragma unroll
                for (int kk = 0; kk < 2; ++kk)
                    kn[f][kk] = *(const f16x8*)&Kb[(size_t)((jt + 1) * 64 + 16 * f + r) * ND + kk * 32 + 8 * g];
        }
        f16x8 vr[4][2];
#pragma unroll
        for (int n = 0; n < 4; ++n)
#pragma unroll
            for (int kk = 0; kk < 2; ++kk)
                vr[n][kk] = *(const f16x8*)&Vb[(size_t)(16 * n + r) * (NB * NN) + jt * 64 + kk * 32 + 8 * g];

        // ---- S tile from current K regs ----
        f32x4 s[4];
#pragma unroll
        for (int f = 0; f < 4; ++f) s[f] = (f32x4){0.f, 0.f, 0.f, 0.f};
#pragma unroll
        for (int f = 0; f < 4; ++f)
#pragma unroll
            for (int kk = 0; kk < 2; ++kk)
                s[f] = __builtin_amdgcn_mfma_f32_16x16x32_f16(qa[kk], kc[f][kk], s[f], 0, 0, 0);
#pragma unroll
        for (int f = 0; f < 4; ++f) s[f] *= SCALE2;

        // ---- online softmax: D layout row = 4g+reg, col = 16f+r ----
        float corr[4];
#pragma unroll
        for (int reg = 0; reg < 4; ++reg) {
            float mx = fmaxf(fmaxf(s[0][reg], s[1][reg]), fmaxf(s[2][reg], s[3][reg]));
            mx = fmaxf(mx, __shfl_xor(mx, 1));
            mx = fmaxf(mx, __shfl_xor(mx, 2));
            mx = fmaxf(mx, __shfl_xor(mx, 4));
            mx = fmaxf(mx, __shfl_xor(mx, 8));
            float mnew = fmaxf(m_i[reg], mx);
            corr[reg] = __expf(m_i[reg] - mnew);
            m_i[reg] = mnew;
            float rs = 0.f;
#pragma unroll
            for (int f = 0; f < 4; ++f) {
                float p = __expf(s[f][reg] - mnew);
                Ps[w][4 * g + reg][16 * f + r] = (_Float16)p;
                rs += p;
            }
            rs += __shfl_xor(rs, 1);
            rs += __shfl_xor(rs, 2);
            rs += __shfl_xor(rs, 4);
            rs += __shfl_xor(rs, 8);
            l_i[reg] = l_i[reg] * corr[reg] + rs;
        }
#pragma unroll
        for (int n = 0; n < 4; ++n)
#pragma unroll
            for (int reg = 0; reg < 4; ++reg) o[n][reg] *= corr[reg];

        // ---- P A-fragments from wave-private LDS (lgkmcnt-ordered, no barrier) ----
        f16x8 pa[2];
#pragma unroll
        for (int kk = 0; kk < 2; ++kk)
            pa[kk] = *(const f16x8*)&Ps[w][r][kk * 32 + 8 * g];

        // ---- PV from prefetched V regs ----
#pragma unroll
        for (int n = 0; n < 4; ++n)
#pragma unroll
            for (int kk = 0; kk < 2; ++kk)
                o[n] = __builtin_amdgcn_mfma_f32_16x16x32_f16(pa[kk], vr[n][kk], o[n], 0, 0, 0);

        if (jt < 15) {
#pragma unroll
            for (int f = 0; f < 4; ++f)
#pragma unroll
                for (int kk = 0; kk < 2; ++kk) kc[f][kk] = kn[f][kk];
        }
    }

    float* Ob = Opre + ((size_t)b * NN + it * 64 + 16 * w) * ND + h * 64;
#pragma unroll
    for (int reg = 0; reg < 4; ++reg) {
        float inv = 1.0f / l_i[reg];
#pragma unroll
        for (int n = 0; n < 4; ++n)
            Ob[(size_t)(4 * g + reg) * ND + 16 * n + r] = o[n][reg] * inv;
    }
}

// ---------------- residual + LayerNorm ----------------
__global__ __launch_bounds__(256) void ln_kernel(const float* __restrict__ Opre,
                                                 const float* __restrict__ Y,
                                                 const float* __restrict__ gamma,
                                                 const float* __restrict__ beta,
                                                 float* __restrict__ Out) {
    const int row = blockIdx.x;   // 0..2047
    const int t = threadIdx.x;
    const float* op = Opre + (size_t)row * ND;
    const float* yp = Y + (size_t)row * ND;
    f32x4 z = *(const f32x4*)&op[t * 4] + *(const f32x4*)&yp[t * 4];

    __shared__ float red[8];
    float s = z.x + z.y + z.z + z.w;
#pragma unroll
    for (int off = 32; off; off >>= 1) s += __shfl_xor(s, off);
    if ((t & 63) == 0) red[t >> 6] = s;
    __syncthreads();
    float mean = (red[0] + red[1] + red[2] + red[3]) * (1.0f / 1024.0f);

    f32x4 d = z - mean;
    float sq = d.x * d.x + d.y * d.y + d.z * d.z + d.w * d.w;
#pragma unroll
    for (int off = 32; off; off >>= 1) sq += __shfl_xor(sq, off);
    if ((t & 63) == 0) red[4 + (t >> 6)] = sq;
    __syncthreads();
    float var = (red[4] + red[5] + red[6] + red[7]) * (1.0f / 1024.0f);
    float rstd = rsqrtf(var + LNEPS);

    f32x4 gg = *(const f32x4*)&gamma[t * 4];
    f32x4 bb = *(const f32x4*)&beta[t * 4];
    f32x4 res = d * rstd * gg + bb;
    *(f32x4*)&Out[(size_t)row * ND + t * 4] = res;
}

// ---------------- launch ----------------
extern "C" void kernel_launch(void* const* d_in, const int* in_sizes, int n_in,
                              void* d_out, int out_size, void* d_ws, size_t ws_size,
                              hipStream_t stream) {
    const float* x = (const float*)d_in[0];
    const float* y = (const float*)d_in[1];
    const float* Wq = (const float*)d_in[2];
    const float* Wk = (const float*)d_in[3];
    const float* Wv = (const float*)d_in[4];
    const float* gamma = (const float*)d_in[5];
    const float* beta = (const float*)d_in[6];
    float* out = (float*)d_out;

    const size_t MB = 1024ull * 1024ull;
    char* w = (char*)d_ws;
    _Float16* xh  = (_Float16*)(w + 0 * MB);    // 4 MB
    _Float16* yh  = (_Float16*)(w + 4 * MB);    // 4 MB
    _Float16* WqT = (_Float16*)(w + 8 * MB);    // 2 MB
    _Float16* WkT = (_Float16*)(w + 10 * MB);   // 2 MB
    _Float16* WvT = (_Float16*)(w + 12 * MB);   // 2 MB
    _Float16* qh  = (_Float16*)(w + 14 * MB);   // 4 MB
    _Float16* khf = (_Float16*)(w + 18 * MB);   // 4 MB  (k, normal layout)
    _Float16* kT  = (_Float16*)(w + 22 * MB);   // 4 MB  (k^T, 1024 x 2048, ld 2048)
    _Float16* vT  = (_Float16*)(w + 26 * MB);   // 4 MB  (v^T, 1024 x 2048, ld 2048)
    _Float16* QKh = (_Float16*)(w + 30 * MB);   // 4 MB
    float* outpre = (float*)(w + 34 * MB);      // 8 MB   (total 42 MB)

    const int NEL = NB * NN * ND;  // 2M

    pack_f16<<<NEL / 1024, 256, 0, stream>>>(x, xh, NEL);
    pack_f16<<<NEL / 1024, 256, 0, stream>>>(y, yh, NEL);

    dim3 tb(32, 8);
    transpose_f2h<<<dim3(32, 32), tb, 0, stream>>>(Wq, WqT, 1024, 1024);
    transpose_f2h<<<dim3(32, 32), tb, 0, stream>>>(Wk, WkT, 1024, 1024);
    transpose_f2h<<<dim3(32, 32), tb, 0, stream>>>(Wv, WvT, 1024, 1024);

    // fused: q, k, k^T, v^T in one 1024-block launch
    gemm_qkv<<<1024, 256, 0, stream>>>(xh, yh, WqT, WkT, WvT, qh, khf, kT, vT);

    // QK[b] = q[b] @ kflat[b]
    gemm_qk<<<dim3(16, 16, 2), 256, 0, stream>>>(qh, kT, QKh);

    // MFMA flash attention + epilogue LN
    flash_mfma<<<dim3(16, 32), 256, 0, stream>>>(QKh, khf, vT, outpre);
    ln_kernel<<<NB * NN, 256, 0, stream>>>(outpre, y, gamma, beta, out);
}

// Round 4
// 131.823 us; speedup vs baseline: 2.7249x; 1.0154x over previous
//
#include <hip/hip_runtime.h>

// Problem constants
#define NB 2
#define NN 1024
#define ND 1024
#define NH 16
#define SCALE2 0.015625f   // (64^-0.5)^2
#define LNEPS 1e-5f
#define BK 32
#define NSPLIT 4
#define JPS (16 / NSPLIT)

typedef _Float16 f16x8 __attribute__((ext_vector_type(8)));
typedef _Float16 f16x4 __attribute__((ext_vector_type(4)));
typedef float f32x4 __attribute__((ext_vector_type(4)));

// ---------------- helpers ----------------
__device__ inline void gload_lds16(const void* g, void* l) {
    __builtin_amdgcn_global_load_lds(
        (const __attribute__((address_space(1))) void*)g,
        (__attribute__((address_space(3))) void*)l, 16, 0, 0);
}

// ---------------- fused prep: pack x,y to f16; transpose Wq,Wk,Wv to f16 ----------------
// blocks 0..1023: pack x | 1024..2047: pack y | 2048..5119: transpose Wq/Wk/Wv (32x32 tiles)
__global__ __launch_bounds__(256) void prep(const float* __restrict__ x,
                                            const float* __restrict__ y,
                                            const float* __restrict__ Wq,
                                            const float* __restrict__ Wk,
                                            const float* __restrict__ Wv,
                                            _Float16* __restrict__ xh,
                                            _Float16* __restrict__ yh,
                                            _Float16* __restrict__ WqT,
                                            _Float16* __restrict__ WkT,
                                            _Float16* __restrict__ WvT) {
    __shared__ float tile[32][33];
    const int bid = blockIdx.x;
    const int tid = threadIdx.x;
    if (bid < 2048) {
        const float* src = (bid < 1024) ? x : y;
        _Float16* dst = (bid < 1024) ? xh : yh;
        int base = (bid & 1023) * 2048 + tid * 8;
        f32x4 a = *(const f32x4*)&src[base];
        f32x4 c = *(const f32x4*)&src[base + 4];
        *(f16x4*)&dst[base] = __builtin_convertvector(a, f16x4);
        *(f16x4*)&dst[base + 4] = __builtin_convertvector(c, f16x4);
    } else {
        int seg = (bid - 2048) >> 10;
        int t = (bid - 2048) & 1023;
        const float* src = seg == 0 ? Wq : seg == 1 ? Wk : Wv;
        _Float16* dst = seg == 0 ? WqT : seg == 1 ? WkT : WvT;
        int tx = tid & 31, ty = tid >> 5;          // (32, 8)
        int c0 = (t & 31) * 32, r0 = (t >> 5) * 32;
#pragma unroll
        for (int i = 0; i < 4; ++i)
            tile[ty + 8 * i][tx] = src[(size_t)(r0 + ty + 8 * i) * 1024 + c0 + tx];
        __syncthreads();
#pragma unroll
        for (int i = 0; i < 4; ++i)
            dst[(size_t)(c0 + ty + 8 * i) * 1024 + r0 + tx] = (_Float16)tile[tx][ty + 8 * i];
    }
}

// ---------------- templated f16 MFMA GEMM body: C(MxN) = A @ BT^T ----------------
template <int BM, int BN>
__device__ __forceinline__ void gemm_body(const _Float16* __restrict__ A,
                                          const _Float16* __restrict__ BT,
                                          _Float16* __restrict__ C,
                                          int lda, int ldb, int ldc,
                                          int brow, int bcol, int K) {
    __shared__ _Float16 Asm[2][BM * BK];
    __shared__ _Float16 Bsm[2][BN * BK];
    constexpr int MR = BM / 32;
    constexpr int NC = BN / 32;
    constexpr int ABYTES = BM * BK * 2;
    constexpr int NLOAD = (BM + BN) * BK * 2 / 4096;
    static_assert(ABYTES % 4096 == 0, "A region must align to load passes");

    const int tid = threadIdx.x;
    const int lane = tid & 63;
    const int w = tid >> 6;
    const int wr = w >> 1, wc = w & 1;
    const int g = lane >> 4, r = lane & 15;

    f32x4 acc[MR][NC];
#pragma unroll
    for (int m = 0; m < MR; ++m)
#pragma unroll
        for (int n = 0; n < NC; ++n) acc[m][n] = (f32x4){0.f, 0.f, 0.f, 0.f};

    auto stage = [&](int buf, int kof) {
#pragma unroll
        for (int itl = 0; itl < NLOAD; ++itl) {
            int o = itl * 4096 + tid * 16;
            if (o < ABYTES) {
                int row = o >> 6, cb = o & 63;
                gload_lds16((const char*)(A + (size_t)(brow + row) * lda + kof) + cb,
                            (char*)Asm[buf] + o);
            } else {
                int o2 = o - ABYTES;
                int row = o2 >> 6, cb = o2 & 63;
                gload_lds16((const char*)(BT + (size_t)(bcol + row) * ldb + kof) + cb,
                            (char*)Bsm[buf] + o2);
            }
        }
    };

    stage(0, 0);
    __syncthreads();

    int cur = 0;
    const int nk = K / BK;
    for (int kt = 0; kt < nk; ++kt) {
        if (kt + 1 < nk) stage(cur ^ 1, (kt + 1) * BK);
        f16x8 af[MR], bf[NC];
#pragma unroll
        for (int m = 0; m < MR; ++m)
            af[m] = *(const f16x8*)&Asm[cur][((BM / 2) * wr + 16 * m + r) * BK + 8 * g];
#pragma unroll
        for (int n = 0; n < NC; ++n)
            bf[n] = *(const f16x8*)&Bsm[cur][((BN / 2) * wc + 16 * n + r) * BK + 8 * g];
#pragma unroll
        for (int m = 0; m < MR; ++m)
#pragma unroll
            for (int n = 0; n < NC; ++n)
                acc[m][n] = __builtin_amdgcn_mfma_f32_16x16x32_f16(af[m], bf[n], acc[m][n], 0, 0, 0);
        __syncthreads();
        cur ^= 1;
    }

    // epilogue: C/D layout col = lane&15, row = (lane>>4)*4 + reg   [m89-verified]
#pragma unroll
    for (int m = 0; m < MR; ++m)
#pragma unroll
        for (int n = 0; n < NC; ++n) {
            int col = bcol + (BN / 2) * wc + 16 * n + r;
#pragma unroll
            for (int r4 = 0; r4 < 4; ++r4) {
                int row = brow + (BM / 2) * wr + 16 * m + 4 * g + r4;
                C[(size_t)row * ldc + col] = (_Float16)acc[m][n][r4];
            }
        }
}

// ---------------- fused QKV(+transposed) GEMM: 4 segments, 1024 blocks ----------------
__global__ __launch_bounds__(256) void gemm_qkv(const _Float16* __restrict__ xh,
                                                const _Float16* __restrict__ yh,
                                                const _Float16* __restrict__ WqT,
                                                const _Float16* __restrict__ WkT,
                                                const _Float16* __restrict__ WvT,
                                                _Float16* __restrict__ qh,
                                                _Float16* __restrict__ khf,
                                                _Float16* __restrict__ kT,
                                                _Float16* __restrict__ vT) {
    const int seg = blockIdx.x >> 8;
    const int t = blockIdx.x & 255;
    const _Float16 *A, *BT;
    _Float16* C;
    int ldc, brow, bcol;
    if (seg == 0)      { A = xh;  BT = WqT; C = qh;  ldc = 1024; brow = (t >> 4) * 128; bcol = (t & 15) * 64; }
    else if (seg == 1) { A = yh;  BT = WkT; C = khf; ldc = 1024; brow = (t >> 4) * 128; bcol = (t & 15) * 64; }
    else if (seg == 2) { A = WkT; BT = yh;  C = kT;  ldc = 2048; brow = (t >> 5) * 128; bcol = (t & 31) * 64; }
    else               { A = WvT; BT = yh;  C = vT;  ldc = 2048; brow = (t >> 5) * 128; bcol = (t & 31) * 64; }
    gemm_body<128, 64>(A, BT, C, 1024, 1024, ldc, brow, bcol, 1024);
}

// ---------------- batched QK GEMM: QK[b] = q[b] @ kflat[b] ----------------
__global__ __launch_bounds__(256) void gemm_qk(const _Float16* __restrict__ qh,
                                               const _Float16* __restrict__ kT,
                                               _Float16* __restrict__ QKh) {
    const int z = blockIdx.z;
    gemm_body<64, 64>(qh + (size_t)z * NN * ND, kT + z * NN, QKh + (size_t)z * NN * ND,
                      1024, 2048, 1024, blockIdx.y * 64, blockIdx.x * 64, 1024);
}

// ---------------- MFMA flash attention, KV-split partials ----------------
// grid (16 it, 32 bh, NSPLIT). 4 waves/block, wave owns 16 Q-rows, JPS KV tiles.
// Writes unnormalized partial O (f16) + per-row m,l.
__global__ __launch_bounds__(256) void flash_part(const _Float16* __restrict__ Qh,
                                                  const _Float16* __restrict__ Kh,
                                                  const _Float16* __restrict__ VT,
                                                  _Float16* __restrict__ opart,
                                                  float* __restrict__ mpart,
                                                  float* __restrict__ lpart) {
    __shared__ _Float16 Ps[4][16][72];
    const int tid = threadIdx.x;
    const int lane = tid & 63;
    const int w = tid >> 6;
    const int g = lane >> 4, r = lane & 15;
    const int it = blockIdx.x;          // 0..15
    const int bh = blockIdx.y;          // 0..31
    const int sp = blockIdx.z;          // 0..NSPLIT-1
    const int b = bh >> 4, h = bh & 15;

    const _Float16* Qb = Qh + ((size_t)b * NN + it * 64 + 16 * w) * ND + h * 64;
    const _Float16* Kb = Kh + (size_t)b * NN * ND + h * 64;
    const _Float16* Vb = VT + (size_t)(h * 64) * (NB * NN) + b * NN;   // ld = 2048

    f16x8 qa[2];
#pragma unroll
    for (int kk = 0; kk < 2; ++kk)
        qa[kk] = *(const f16x8*)&Qb[(size_t)r * ND + kk * 32 + 8 * g];

    float m_i[4], l_i[4];
    f32x4 o[4];
#pragma unroll
    for (int i = 0; i < 4; ++i) { m_i[i] = -1e30f; l_i[i] = 0.f; o[i] = (f32x4){0.f,0.f,0.f,0.f}; }

    for (int jt = sp * JPS; jt < sp * JPS + JPS; ++jt) {
        // ---- S tile ----
        f32x4 s[4];
#pragma unroll
        for (int f = 0; f < 4; ++f) s[f] = (f32x4){0.f, 0.f, 0.f, 0.f};
#pragma unroll
        for (int f = 0; f < 4; ++f)
#pragma unroll
            for (int kk = 0; kk < 2; ++kk) {
                f16x8 kb = *(const f16x8*)&Kb[(size_t)(jt * 64 + 16 * f + r) * ND + kk * 32 + 8 * g];
                s[f] = __builtin_amdgcn_mfma_f32_16x16x32_f16(qa[kk], kb, s[f], 0, 0, 0);
            }
#pragma unroll
        for (int f = 0; f < 4; ++f) s[f] *= SCALE2;

        // ---- online softmax: D layout row = 4g+reg, col = 16f+r ----
        float corr[4];
#pragma unroll
        for (int reg = 0; reg < 4; ++reg) {
            float mx = fmaxf(fmaxf(s[0][reg], s[1][reg]), fmaxf(s[2][reg], s[3][reg]));
            mx = fmaxf(mx, __shfl_xor(mx, 1));
            mx = fmaxf(mx, __shfl_xor(mx, 2));
            mx = fmaxf(mx, __shfl_xor(mx, 4));
            mx = fmaxf(mx, __shfl_xor(mx, 8));
            float mnew = fmaxf(m_i[reg], mx);
            corr[reg] = __expf(m_i[reg] - mnew);
            m_i[reg] = mnew;
            float rs = 0.f;
#pragma unroll
            for (int f = 0; f < 4; ++f) {
                float p = __expf(s[f][reg] - mnew);
                Ps[w][4 * g + reg][16 * f + r] = (_Float16)p;
                rs += p;
            }
            rs += __shfl_xor(rs, 1);
            rs += __shfl_xor(rs, 2);
            rs += __shfl_xor(rs, 4);
            rs += __shfl_xor(rs, 8);
            l_i[reg] = l_i[reg] * corr[reg] + rs;
        }
#pragma unroll
        for (int n = 0; n < 4; ++n)
#pragma unroll
            for (int reg = 0; reg < 4; ++reg) o[n][reg] *= corr[reg];

        // ---- P A-fragments from wave-private LDS (lgkmcnt-ordered, no barrier) ----
        f16x8 pa[2];
#pragma unroll
        for (int kk = 0; kk < 2; ++kk)
            pa[kk] = *(const f16x8*)&Ps[w][r][kk * 32 + 8 * g];

        // ---- PV ----
#pragma unroll
        for (int n = 0; n < 4; ++n)
#pragma unroll
            for (int kk = 0; kk < 2; ++kk) {
                f16x8 vb = *(const f16x8*)&Vb[(size_t)(16 * n + r) * (NB * NN) + jt * 64 + kk * 32 + 8 * g];
                o[n] = __builtin_amdgcn_mfma_f32_16x16x32_f16(pa[kk], vb, o[n], 0, 0, 0);
            }
    }

    // epilogue: unnormalized partial O (f16) + m,l per row
    _Float16* Ob = opart + (size_t)sp * NB * NN * ND + ((size_t)b * NN + it * 64 + 16 * w) * ND + h * 64;
#pragma unroll
    for (int reg = 0; reg < 4; ++reg)
#pragma unroll
        for (int n = 0; n < 4; ++n)
            Ob[(size_t)(4 * g + reg) * ND + 16 * n + r] = (_Float16)o[n][reg];

    if (r == 0) {
        int base = (((sp * NB) + b) * NH + h) * NN + it * 64 + 16 * w + 4 * g;
#pragma unroll
        for (int reg = 0; reg < 4; ++reg) {
            mpart[base + reg] = m_i[reg];
            lpart[base + reg] = l_i[reg];
        }
    }
}

// ---------------- combine partials + residual + LayerNorm ----------------
__global__ __launch_bounds__(256) void ln_combine(const _Float16* __restrict__ opart,
                                                  const float* __restrict__ mpart,
                                                  const float* __restrict__ lpart,
                                                  const float* __restrict__ Y,
                                                  const float* __restrict__ gamma,
                                                  const float* __restrict__ beta,
                                                  float* __restrict__ Out) {
    const int row = blockIdx.x;   // b*NN + n
    const int b = row >> 10, n = row & 1023;
    const int t = threadIdx.x;
    const int c0 = t * 4;
    const int h = c0 >> 6;

    float ms[NSPLIT], ls[NSPLIT];
    float M = -1e30f;
#pragma unroll
    for (int s = 0; s < NSPLIT; ++s) {
        int idx = (((s * NB) + b) * NH + h) * NN + n;
        ms[s] = mpart[idx];
        ls[s] = lpart[idx];
        M = fmaxf(M, ms[s]);
    }
    float L = 0.f;
    float es[NSPLIT];
#pragma unroll
    for (int s = 0; s < NSPLIT; ++s) { es[s] = __expf(ms[s] - M); L += es[s] * ls[s]; }

    f32x4 acc = (f32x4){0.f, 0.f, 0.f, 0.f};
#pragma unroll
    for (int s = 0; s < NSPLIT; ++s) {
        f16x4 ov = *(const f16x4*)&opart[(size_t)s * NB * NN * ND + (size_t)row * ND + c0];
        acc += es[s] * __builtin_convertvector(ov, f32x4);
    }
    f32x4 z = acc * (1.0f / L) + *(const f32x4*)&Y[(size_t)row * ND + c0];

    __shared__ float red[8];
    float s1 = z.x + z.y + z.z + z.w;
#pragma unroll
    for (int off = 32; off; off >>= 1) s1 += __shfl_xor(s1, off);
    if ((t & 63) == 0) red[t >> 6] = s1;
    __syncthreads();
    float mean = (red[0] + red[1] + red[2] + red[3]) * (1.0f / 1024.0f);

    f32x4 d = z - mean;
    float sq = d.x * d.x + d.y * d.y + d.z * d.z + d.w * d.w;
#pragma unroll
    for (int off = 32; off; off >>= 1) sq += __shfl_xor(sq, off);
    if ((t & 63) == 0) red[4 + (t >> 6)] = sq;
    __syncthreads();
    float var = (red[4] + red[5] + red[6] + red[7]) * (1.0f / 1024.0f);
    float rstd = rsqrtf(var + LNEPS);

    f32x4 gg = *(const f32x4*)&gamma[c0];
    f32x4 bb = *(const f32x4*)&beta[c0];
    f32x4 res = d * rstd * gg + bb;
    *(f32x4*)&Out[(size_t)row * ND + c0] = res;
}

// ---------------- launch ----------------
extern "C" void kernel_launch(void* const* d_in, const int* in_sizes, int n_in,
                              void* d_out, int out_size, void* d_ws, size_t ws_size,
                              hipStream_t stream) {
    const float* x = (const float*)d_in[0];
    const float* y = (const float*)d_in[1];
    const float* Wq = (const float*)d_in[2];
    const float* Wk = (const float*)d_in[3];
    const float* Wv = (const float*)d_in[4];
    const float* gamma = (const float*)d_in[5];
    const float* beta = (const float*)d_in[6];
    float* out = (float*)d_out;

    const size_t MB = 1024ull * 1024ull;
    char* w = (char*)d_ws;
    _Float16* xh  = (_Float16*)(w + 0 * MB);    // 4 MB
    _Float16* yh  = (_Float16*)(w + 4 * MB);    // 4 MB
    _Float16* WqT = (_Float16*)(w + 8 * MB);    // 2 MB
    _Float16* WkT = (_Float16*)(w + 10 * MB);   // 2 MB
    _Float16* WvT = (_Float16*)(w + 12 * MB);   // 2 MB
    _Float16* qh  = (_Float16*)(w + 14 * MB);   // 4 MB
    _Float16* khf = (_Float16*)(w + 18 * MB);   // 4 MB  (k, row-major)
    _Float16* kT  = (_Float16*)(w + 22 * MB);   // 4 MB  (k^T, ld 2048)
    _Float16* vT  = (_Float16*)(w + 26 * MB);   // 4 MB  (v^T, ld 2048)
    _Float16* QKh = (_Float16*)(w + 30 * MB);   // 4 MB
    _Float16* opart = (_Float16*)(w + 34 * MB); // 16 MB (NSPLIT x 2048 x 1024 f16)
    float* mpart = (float*)(w + 50 * MB);       // 0.5 MB
    float* lpart = (float*)(w + 50 * MB + 512 * 1024);  // 0.5 MB  (total 51 MB)

    prep<<<5120, 256, 0, stream>>>(x, y, Wq, Wk, Wv, xh, yh, WqT, WkT, WvT);

    gemm_qkv<<<1024, 256, 0, stream>>>(xh, yh, WqT, WkT, WvT, qh, khf, kT, vT);

    gemm_qk<<<dim3(16, 16, 2), 256, 0, stream>>>(qh, kT, QKh);

    flash_part<<<dim3(16, 32, NSPLIT), 256, 0, stream>>>(QKh, khf, vT, opart, mpart, lpart);

    ln_combine<<<NB * NN, 256, 0, stream>>>(opart, mpart, lpart, y, gamma, beta, out);
}

// Round 5
// 111.880 us; speedup vs baseline: 3.2106x; 1.1783x over previous
//
#include <hip/hip_runtime.h>

// Problem constants
#define NB 2
#define NN 1024
#define ND 1024
#define NH 16
#define SCALE2 0.015625f   // (64^-0.5)^2
#define LNEPS 1e-5f
#define BK 32
#define NSPLIT 4
#define JPS (16 / NSPLIT)

typedef _Float16 f16x8 __attribute__((ext_vector_type(8)));
typedef _Float16 f16x4 __attribute__((ext_vector_type(4)));
typedef float f32x4 __attribute__((ext_vector_type(4)));

// Fragment-linear layout (per b,h head): operand fragments for mfma_16x16x32_f16
// stored so one wave-load of f16x8 covers a contiguous 1KB block.
//   chunk(lane) = (r*4 + g), r=lane&15, g=lane>>4 ; element = chunk*8 + e
//   Q/K block key: (row16_block, kk)  -> flat = ((bh*64 + R16)*2 + kk)*512 + chunk*8 + e
//   V   block key: (n, jt, kk)        -> flat = ((bh*4+n)*16+jt)*2+kk)*512 + chunk*8 + e

// ---------------- helpers ----------------
__device__ inline void gload_lds16(const void* g, void* l) {
    __builtin_amdgcn_global_load_lds(
        (const __attribute__((address_space(1))) void*)g,
        (__attribute__((address_space(3))) void*)l, 16, 0, 0);
}

// ---------------- fused prep: pack x,y to f16; transpose Wq,Wk,Wv to f16 ----------------
__global__ __launch_bounds__(256) void prep(const float* __restrict__ x,
                                            const float* __restrict__ y,
                                            const float* __restrict__ Wq,
                                            const float* __restrict__ Wk,
                                            const float* __restrict__ Wv,
                                            _Float16* __restrict__ xh,
                                            _Float16* __restrict__ yh,
                                            _Float16* __restrict__ WqT,
                                            _Float16* __restrict__ WkT,
                                            _Float16* __restrict__ WvT) {
    __shared__ float tile[32][33];
    const int bid = blockIdx.x;
    const int tid = threadIdx.x;
    if (bid < 2048) {
        const float* src = (bid < 1024) ? x : y;
        _Float16* dst = (bid < 1024) ? xh : yh;
        int base = (bid & 1023) * 2048 + tid * 8;
        f32x4 a = *(const f32x4*)&src[base];
        f32x4 c = *(const f32x4*)&src[base + 4];
        *(f16x4*)&dst[base] = __builtin_convertvector(a, f16x4);
        *(f16x4*)&dst[base + 4] = __builtin_convertvector(c, f16x4);
    } else {
        int seg = (bid - 2048) >> 10;
        int t = (bid - 2048) & 1023;
        const float* src = seg == 0 ? Wq : seg == 1 ? Wk : Wv;
        _Float16* dst = seg == 0 ? WqT : seg == 1 ? WkT : WvT;
        int tx = tid & 31, ty = tid >> 5;          // (32, 8)
        int c0 = (t & 31) * 32, r0 = (t >> 5) * 32;
#pragma unroll
        for (int i = 0; i < 4; ++i)
            tile[ty + 8 * i][tx] = src[(size_t)(r0 + ty + 8 * i) * 1024 + c0 + tx];
        __syncthreads();
#pragma unroll
        for (int i = 0; i < 4; ++i)
            dst[(size_t)(c0 + ty + 8 * i) * 1024 + r0 + tx] = (_Float16)tile[tx][ty + 8 * i];
    }
}

// ---------------- f16 MFMA GEMM body with mode-dispatched epilogue ----------------
// C(MxN) = A(M x K) @ BT(N x K)^T. 4 waves 2x2, double-buffered LDS, global_load_lds(16B).
// mode 0: row-major f16, ldc       (out0)
// mode 1: K-fragment layout        (out0 = kfrag)
// mode 2: row-major f16, ldc       (out0 = kT, ldc 2048)
// mode 3: V-fragment layout        (out0 = vfrag)
// mode 4: Q-fragment layout        (out0 = qfrag, zoff = b)
template <int BM, int BN>
__device__ __forceinline__ void gemm_body(const _Float16* __restrict__ A,
                                          const _Float16* __restrict__ BT,
                                          int lda, int ldb,
                                          int brow, int bcol, int K,
                                          int mode, _Float16* __restrict__ out0,
                                          int ldc, int zoff) {
    __shared__ _Float16 Asm[2][BM * BK];
    __shared__ _Float16 Bsm[2][BN * BK];
    constexpr int MR = BM / 32;
    constexpr int NC = BN / 32;
    constexpr int ABYTES = BM * BK * 2;
    constexpr int NLOAD = (BM + BN) * BK * 2 / 4096;
    static_assert(ABYTES % 4096 == 0, "A region must align to load passes");

    const int tid = threadIdx.x;
    const int lane = tid & 63;
    const int w = tid >> 6;
    const int wr = w >> 1, wc = w & 1;
    const int g = lane >> 4, r = lane & 15;

    f32x4 acc[MR][NC];
#pragma unroll
    for (int m = 0; m < MR; ++m)
#pragma unroll
        for (int n = 0; n < NC; ++n) acc[m][n] = (f32x4){0.f, 0.f, 0.f, 0.f};

    auto stage = [&](int buf, int kof) {
#pragma unroll
        for (int itl = 0; itl < NLOAD; ++itl) {
            int o = itl * 4096 + tid * 16;
            if (o < ABYTES) {
                int row = o >> 6, cb = o & 63;
                gload_lds16((const char*)(A + (size_t)(brow + row) * lda + kof) + cb,
                            (char*)Asm[buf] + o);
            } else {
                int o2 = o - ABYTES;
                int row = o2 >> 6, cb = o2 & 63;
                gload_lds16((const char*)(BT + (size_t)(bcol + row) * ldb + kof) + cb,
                            (char*)Bsm[buf] + o2);
            }
        }
    };

    stage(0, 0);
    __syncthreads();

    int cur = 0;
    const int nk = K / BK;
    for (int kt = 0; kt < nk; ++kt) {
        if (kt + 1 < nk) stage(cur ^ 1, (kt + 1) * BK);
        f16x8 af[MR], bf[NC];
#pragma unroll
        for (int m = 0; m < MR; ++m)
            af[m] = *(const f16x8*)&Asm[cur][((BM / 2) * wr + 16 * m + r) * BK + 8 * g];
#pragma unroll
        for (int n = 0; n < NC; ++n)
            bf[n] = *(const f16x8*)&Bsm[cur][((BN / 2) * wc + 16 * n + r) * BK + 8 * g];
#pragma unroll
        for (int m = 0; m < MR; ++m)
#pragma unroll
            for (int n = 0; n < NC; ++n)
                acc[m][n] = __builtin_amdgcn_mfma_f32_16x16x32_f16(af[m], bf[n], acc[m][n], 0, 0, 0);
        __syncthreads();
        cur ^= 1;
    }

    // epilogue: C/D layout col = lane&15, row = (lane>>4)*4 + reg   [m89-verified]
#pragma unroll
    for (int m = 0; m < MR; ++m)
#pragma unroll
        for (int n = 0; n < NC; ++n)
#pragma unroll
            for (int r4 = 0; r4 < 4; ++r4) {
                int row = brow + (BM / 2) * wr + 16 * m + 4 * g + r4;
                int col = bcol + (BN / 2) * wc + 16 * n + r;
                _Float16 val = (_Float16)acc[m][n][r4];
                if (mode == 0 || mode == 2) {
                    out0[(size_t)row * ldc + col] = val;
                } else if (mode == 1) {
                    // k[b][kv][h*64+dh] -> kfrag
                    int bb = row >> 10, kv = row & 1023, hh = col >> 6, dh = col & 63;
                    size_t flat = (((size_t)((bb * 16 + hh) * 64 + (kv >> 4)) * 2 + (dh >> 5)) << 9)
                                  + (((kv & 15) * 4 + ((dh >> 3) & 3)) << 3) + (dh & 7);
                    out0[flat] = val;
                } else if (mode == 3) {
                    // vT[dh_global][b*1024+kv] -> vfrag
                    int hh = row >> 6, dsub = row & 63;
                    int bb = col >> 10, kv = col & 1023;
                    size_t flat = (((size_t)((((bb * 16 + hh) * 4 + (dsub >> 4)) * 16 + (kv >> 6)) * 2
                                             + ((kv >> 5) & 1))) << 9)
                                  + (((dsub & 15) * 4 + ((kv >> 3) & 3)) << 3) + (kv & 7);
                    out0[flat] = val;
                } else {
                    // QK[b][i][h*64+dh] -> qfrag (zoff = b)
                    int hh = col >> 6, dh = col & 63;
                    size_t flat = (((size_t)((zoff * 16 + hh) * 64 + (row >> 4)) * 2 + (dh >> 5)) << 9)
                                  + (((row & 15) * 4 + ((dh >> 3) & 3)) << 3) + (dh & 7);
                    out0[flat] = val;
                }
            }
}

// ---------------- fused QKV GEMM: 4 segments, 1024 blocks ----------------
// seg0: qh    = xh @ Wq      (2048x1024 row-major, feeds gemm_qk A)
// seg1: kfrag = yh @ Wk      (fragment layout, feeds flash K)
// seg2: kT    = WkT @ yh^T   (1024x2048 row-major, feeds gemm_qk BT)
// seg3: vfrag = WvT @ yh^T   (fragment layout, feeds flash V)
__global__ __launch_bounds__(256) void gemm_qkv(const _Float16* __restrict__ xh,
                                                const _Float16* __restrict__ yh,
                                                const _Float16* __restrict__ WqT,
                                                const _Float16* __restrict__ WkT,
                                                const _Float16* __restrict__ WvT,
                                                _Float16* __restrict__ qh,
                                                _Float16* __restrict__ kfrag,
                                                _Float16* __restrict__ kT,
                                                _Float16* __restrict__ vfrag) {
    const int seg = blockIdx.x >> 8;
    const int t = blockIdx.x & 255;
    const _Float16 *A, *BT;
    _Float16* out;
    int ldc, brow, bcol, mode;
    if (seg == 0)      { A = xh;  BT = WqT; out = qh;    mode = 0; ldc = 1024; brow = (t >> 4) * 128; bcol = (t & 15) * 64; }
    else if (seg == 1) { A = yh;  BT = WkT; out = kfrag; mode = 1; ldc = 0;    brow = (t >> 4) * 128; bcol = (t & 15) * 64; }
    else if (seg == 2) { A = WkT; BT = yh;  out = kT;    mode = 2; ldc = 2048; brow = (t >> 5) * 128; bcol = (t & 31) * 64; }
    else               { A = WvT; BT = yh;  out = vfrag; mode = 3; ldc = 0;    brow = (t >> 5) * 128; bcol = (t & 31) * 64; }
    gemm_body<128, 64>(A, BT, 1024, 1024, brow, bcol, 1024, mode, out, ldc, 0);
}

// ---------------- batched QK GEMM: qfrag[b] = (q[b] @ kflat[b]) in fragment layout ----------------
__global__ __launch_bounds__(256) void gemm_qk(const _Float16* __restrict__ qh,
                                               const _Float16* __restrict__ kT,
                                               _Float16* __restrict__ qfrag) {
    const int z = blockIdx.z;
    gemm_body<64, 64>(qh + (size_t)z * NN * ND, kT + z * NN, 1024, 2048,
                      blockIdx.y * 64, blockIdx.x * 64, 1024, 4, qfrag, 0, z);
}

// ---------------- MFMA flash attention, KV-split partials, fragment-linear operands ----------------
__global__ __launch_bounds__(256) void flash_part(const _Float16* __restrict__ Qfrag,
                                                  const _Float16* __restrict__ Kfrag,
                                                  const _Float16* __restrict__ Vfrag,
                                                  _Float16* __restrict__ opart,
                                                  float* __restrict__ mpart,
                                                  float* __restrict__ lpart) {
    __shared__ _Float16 Ps[4][16][72];
    const int tid = threadIdx.x;
    const int lane = tid & 63;
    const int w = tid >> 6;
    const int g = lane >> 4, r = lane & 15;
    const int it = blockIdx.x;          // 0..15
    const int bh = blockIdx.y;          // 0..31
    const int sp = blockIdx.z;          // 0..NSPLIT-1
    const int b = bh >> 4, h = bh & 15;

    const size_t bh64 = (size_t)bh < 16 ? (size_t)(b * 16 + h) : (size_t)(b * 16 + h); // = b*16+h
    const int ch8 = ((r << 2) + g) << 3;   // lane's chunk offset (f16) within a 1KB fragment block

    const _Float16* Qf = Qfrag + (((bh64 * 64) + it * 4 + w) << 10);
    const _Float16* Kf = Kfrag + (bh64 << 16);
    const _Float16* Vf = Vfrag + (bh64 << 16);

    f16x8 qa[2];
#pragma unroll
    for (int kk = 0; kk < 2; ++kk)
        qa[kk] = *(const f16x8*)&Qf[kk * 512 + ch8];

    float m_i[4], l_i[4];
    f32x4 o[4];
#pragma unroll
    for (int i = 0; i < 4; ++i) { m_i[i] = -1e30f; l_i[i] = 0.f; o[i] = (f32x4){0.f,0.f,0.f,0.f}; }

    for (int jt = sp * JPS; jt < sp * JPS + JPS; ++jt) {
        // ---- coalesced fragment loads: each is one contiguous 1KB wave-read ----
        f16x8 kfr[4][2], vfr[4][2];
#pragma unroll
        for (int f = 0; f < 4; ++f)
#pragma unroll
            for (int kk = 0; kk < 2; ++kk)
                kfr[f][kk] = *(const f16x8*)&Kf[(jt * 4 + f) * 1024 + kk * 512 + ch8];
#pragma unroll
        for (int n = 0; n < 4; ++n)
#pragma unroll
            for (int kk = 0; kk < 2; ++kk)
                vfr[n][kk] = *(const f16x8*)&Vf[(n * 16 + jt) * 1024 + kk * 512 + ch8];

        // ---- S tile ----
        f32x4 s[4];
#pragma unroll
        for (int f = 0; f < 4; ++f) s[f] = (f32x4){0.f, 0.f, 0.f, 0.f};
#pragma unroll
        for (int f = 0; f < 4; ++f)
#pragma unroll
            for (int kk = 0; kk < 2; ++kk)
                s[f] = __builtin_amdgcn_mfma_f32_16x16x32_f16(qa[kk], kfr[f][kk], s[f], 0, 0, 0);
#pragma unroll
        for (int f = 0; f < 4; ++f) s[f] *= SCALE2;

        // ---- online softmax: D layout row = 4g+reg, col = 16f+r ----
        float corr[4];
#pragma unroll
        for (int reg = 0; reg < 4; ++reg) {
            float mx = fmaxf(fmaxf(s[0][reg], s[1][reg]), fmaxf(s[2][reg], s[3][reg]));
            mx = fmaxf(mx, __shfl_xor(mx, 1));
            mx = fmaxf(mx, __shfl_xor(mx, 2));
            mx = fmaxf(mx, __shfl_xor(mx, 4));
            mx = fmaxf(mx, __shfl_xor(mx, 8));
            float mnew = fmaxf(m_i[reg], mx);
            corr[reg] = __expf(m_i[reg] - mnew);
            m_i[reg] = mnew;
            float rs = 0.f;
#pragma unroll
            for (int f = 0; f < 4; ++f) {
                float p = __expf(s[f][reg] - mnew);
                Ps[w][4 * g + reg][16 * f + r] = (_Float16)p;
                rs += p;
            }
            rs += __shfl_xor(rs, 1);
            rs += __shfl_xor(rs, 2);
            rs += __shfl_xor(rs, 4);
            rs += __shfl_xor(rs, 8);
            l_i[reg] = l_i[reg] * corr[reg] + rs;
        }
#pragma unroll
        for (int n = 0; n < 4; ++n)
#pragma unroll
            for (int reg = 0; reg < 4; ++reg) o[n][reg] *= corr[reg];

        // ---- P A-fragments from wave-private LDS (lgkmcnt-ordered, no barrier) ----
        f16x8 pa[2];
#pragma unroll
        for (int kk = 0; kk < 2; ++kk)
            pa[kk] = *(const f16x8*)&Ps[w][r][kk * 32 + 8 * g];

        // ---- PV ----
#pragma unroll
        for (int n = 0; n < 4; ++n)
#pragma unroll
            for (int kk = 0; kk < 2; ++kk)
                o[n] = __builtin_amdgcn_mfma_f32_16x16x32_f16(pa[kk], vfr[n][kk], o[n], 0, 0, 0);
    }

    // epilogue: unnormalized partial O (f16) + m,l per row
    _Float16* Ob = opart + (size_t)sp * NB * NN * ND + ((size_t)b * NN + it * 64 + 16 * w) * ND + h * 64;
#pragma unroll
    for (int reg = 0; reg < 4; ++reg)
#pragma unroll
        for (int n = 0; n < 4; ++n)
            Ob[(size_t)(4 * g + reg) * ND + 16 * n + r] = (_Float16)o[n][reg];

    if (r == 0) {
        int base = (((sp * NB) + b) * NH + h) * NN + it * 64 + 16 * w + 4 * g;
#pragma unroll
        for (int reg = 0; reg < 4; ++reg) {
            mpart[base + reg] = m_i[reg];
            lpart[base + reg] = l_i[reg];
        }
    }
}

// ---------------- combine partials + residual + LayerNorm ----------------
__global__ __launch_bounds__(256) void ln_combine(const _Float16* __restrict__ opart,
                                                  const float* __restrict__ mpart,
                                                  const float* __restrict__ lpart,
                                                  const float* __restrict__ Y,
                                                  const float* __restrict__ gamma,
                                                  const float* __restrict__ beta,
                                                  float* __restrict__ Out) {
    const int row = blockIdx.x;   // b*NN + n
    const int b = row >> 10, n = row & 1023;
    const int t = threadIdx.x;
    const int c0 = t * 4;
    const int h = c0 >> 6;

    float ms[NSPLIT], ls[NSPLIT];
    float M = -1e30f;
#pragma unroll
    for (int s = 0; s < NSPLIT; ++s) {
        int idx = (((s * NB) + b) * NH + h) * NN + n;
        ms[s] = mpart[idx];
        ls[s] = lpart[idx];
        M = fmaxf(M, ms[s]);
    }
    float L = 0.f;
    float es[NSPLIT];
#pragma unroll
    for (int s = 0; s < NSPLIT; ++s) { es[s] = __expf(ms[s] - M); L += es[s] * ls[s]; }

    f32x4 acc = (f32x4){0.f, 0.f, 0.f, 0.f};
#pragma unroll
    for (int s = 0; s < NSPLIT; ++s) {
        f16x4 ov = *(const f16x4*)&opart[(size_t)s * NB * NN * ND + (size_t)row * ND + c0];
        acc += es[s] * __builtin_convertvector(ov, f32x4);
    }
    f32x4 z = acc * (1.0f / L) + *(const f32x4*)&Y[(size_t)row * ND + c0];

    __shared__ float red[8];
    float s1 = z.x + z.y + z.z + z.w;
#pragma unroll
    for (int off = 32; off; off >>= 1) s1 += __shfl_xor(s1, off);
    if ((t & 63) == 0) red[t >> 6] = s1;
    __syncthreads();
    float mean = (red[0] + red[1] + red[2] + red[3]) * (1.0f / 1024.0f);

    f32x4 d = z - mean;
    float sq = d.x * d.x + d.y * d.y + d.z * d.z + d.w * d.w;
#pragma unroll
    for (int off = 32; off; off >>= 1) sq += __shfl_xor(sq, off);
    if ((t & 63) == 0) red[4 + (t >> 6)] = sq;
    __syncthreads();
    float var = (red[4] + red[5] + red[6] + red[7]) * (1.0f / 1024.0f);
    float rstd = rsqrtf(var + LNEPS);

    f32x4 gg = *(const f32x4*)&gamma[c0];
    f32x4 bb = *(const f32x4*)&beta[c0];
    f32x4 res = d * rstd * gg + bb;
    *(f32x4*)&Out[(size_t)row * ND + c0] = res;
}

// ---------------- launch ----------------
extern "C" void kernel_launch(void* const* d_in, const int* in_sizes, int n_in,
                              void* d_out, int out_size, void* d_ws, size_t ws_size,
                              hipStream_t stream) {
    const float* x = (const float*)d_in[0];
    const float* y = (const float*)d_in[1];
    const float* Wq = (const float*)d_in[2];
    const float* Wk = (const float*)d_in[3];
    const float* Wv = (const float*)d_in[4];
    const float* gamma = (const float*)d_in[5];
    const float* beta = (const float*)d_in[6];
    float* out = (float*)d_out;

    const size_t MB = 1024ull * 1024ull;
    char* w = (char*)d_ws;
    _Float16* xh    = (_Float16*)(w + 0 * MB);    // 4 MB
    _Float16* yh    = (_Float16*)(w + 4 * MB);    // 4 MB
    _Float16* WqT   = (_Float16*)(w + 8 * MB);    // 2 MB
    _Float16* WkT   = (_Float16*)(w + 10 * MB);   // 2 MB
    _Float16* WvT   = (_Float16*)(w + 12 * MB);   // 2 MB
    _Float16* qh    = (_Float16*)(w + 14 * MB);   // 4 MB
    _Float16* kT    = (_Float16*)(w + 18 * MB);   // 4 MB  (k^T, ld 2048)
    _Float16* kfrag = (_Float16*)(w + 22 * MB);   // 4 MB  (K fragment layout)
    _Float16* vfrag = (_Float16*)(w + 26 * MB);   // 4 MB  (V fragment layout)
    _Float16* qfrag = (_Float16*)(w + 30 * MB);   // 4 MB  (Q' fragment layout)
    _Float16* opart = (_Float16*)(w + 34 * MB);   // 16 MB (NSPLIT x 2048 x 1024 f16)
    float* mpart = (float*)(w + 50 * MB);         // 0.5 MB
    float* lpart = (float*)(w + 50 * MB + 512 * 1024);  // 0.5 MB  (total 51 MB)

    prep<<<5120, 256, 0, stream>>>(x, y, Wq, Wk, Wv, xh, yh, WqT, WkT, WvT);

    gemm_qkv<<<1024, 256, 0, stream>>>(xh, yh, WqT, WkT, WvT, qh, kfrag, kT, vfrag);

    gemm_qk<<<dim3(16, 16, 2), 256, 0, stream>>>(qh, kT, qfrag);

    flash_part<<<dim3(16, 32, NSPLIT), 256, 0, stream>>>(qfrag, kfrag, vfrag, opart, mpart, lpart);

    ln_combine<<<NB * NN, 256, 0, stream>>>(opart, mpart, lpart, y, gamma, beta, out);
}

// Round 6
// 98.799 us; speedup vs baseline: 3.6357x; 1.1324x over previous
//
#include <hip/hip_runtime.h>

// Problem constants
#define NB 2
#define NN 1024
#define ND 1024
#define NH 16
#define SCALE2 0.015625f   // (64^-0.5)^2
#define LNEPS 1e-5f
#define BK 32
#define NSPLIT 4
#define JPS (16 / NSPLIT)

typedef _Float16 f16x8 __attribute__((ext_vector_type(8)));
typedef _Float16 f16x4 __attribute__((ext_vector_type(4)));
typedef float f32x4 __attribute__((ext_vector_type(4)));

// Fragment-linear layout (per b,h head): operand fragments for mfma_16x16x32_f16
// stored so one wave-load of f16x8 covers a contiguous 1KB block.
//   chunk(lane) = (r*4 + g), r=lane&15, g=lane>>4 ; element = chunk*8 + e
//   Q/K block key: (row16_block, kk)  -> flat = ((bh*64 + R16)*2 + kk)*512 + chunk*8 + e
//   V   block key: (n, jt, kk)        -> flat = (((bh*4+n)*16+jt)*2+kk)*512 + chunk*8 + e

// ---------------- helpers ----------------
__device__ inline void gload_lds16(const void* g, void* l) {
    __builtin_amdgcn_global_load_lds(
        (const __attribute__((address_space(1))) void*)g,
        (__attribute__((address_space(3))) void*)l, 16, 0, 0);
}

__device__ inline f32x4 vmax4(f32x4 a, f32x4 b) {
    f32x4 c;
    c[0] = fmaxf(a[0], b[0]); c[1] = fmaxf(a[1], b[1]);
    c[2] = fmaxf(a[2], b[2]); c[3] = fmaxf(a[3], b[3]);
    return c;
}

// ---------------- fused prep: pack x,y to f16; transpose Wq,Wk,Wv to f16 ----------------
__global__ __launch_bounds__(256) void prep(const float* __restrict__ x,
                                            const float* __restrict__ y,
                                            const float* __restrict__ Wq,
                                            const float* __restrict__ Wk,
                                            const float* __restrict__ Wv,
                                            _Float16* __restrict__ xh,
                                            _Float16* __restrict__ yh,
                                            _Float16* __restrict__ WqT,
                                            _Float16* __restrict__ WkT,
                                            _Float16* __restrict__ WvT) {
    __shared__ float tile[32][33];
    const int bid = blockIdx.x;
    const int tid = threadIdx.x;
    if (bid < 2048) {
        const float* src = (bid < 1024) ? x : y;
        _Float16* dst = (bid < 1024) ? xh : yh;
        int base = (bid & 1023) * 2048 + tid * 8;
        f32x4 a = *(const f32x4*)&src[base];
        f32x4 c = *(const f32x4*)&src[base + 4];
        *(f16x4*)&dst[base] = __builtin_convertvector(a, f16x4);
        *(f16x4*)&dst[base + 4] = __builtin_convertvector(c, f16x4);
    } else {
        int seg = (bid - 2048) >> 10;
        int t = (bid - 2048) & 1023;
        const float* src = seg == 0 ? Wq : seg == 1 ? Wk : Wv;
        _Float16* dst = seg == 0 ? WqT : seg == 1 ? WkT : WvT;
        int tx = tid & 31, ty = tid >> 5;          // (32, 8)
        int c0 = (t & 31) * 32, r0 = (t >> 5) * 32;
#pragma unroll
        for (int i = 0; i < 4; ++i)
            tile[ty + 8 * i][tx] = src[(size_t)(r0 + ty + 8 * i) * 1024 + c0 + tx];
        __syncthreads();
#pragma unroll
        for (int i = 0; i < 4; ++i)
            dst[(size_t)(c0 + ty + 8 * i) * 1024 + r0 + tx] = (_Float16)tile[tx][ty + 8 * i];
    }
}

// ---------------- f16 MFMA GEMM body with mode-dispatched epilogue ----------------
// C(MxN) = A(M x K) @ BT(N x K)^T. 4 waves 2x2, double-buffered LDS, global_load_lds(16B).
// mode 0: row-major f16 out0, ldc
// mode 1: K dual-write: out0 = kfrag (fragment layout), out1 = kT (col-major, ld 2048)
// mode 3: V-fragment layout (out0 = vfrag)
// mode 4: Q-fragment layout (out0 = qfrag, zoff = b), value scaled by SCALE2
template <int BM, int BN>
__device__ __forceinline__ void gemm_body(const _Float16* __restrict__ A,
                                          const _Float16* __restrict__ BT,
                                          int lda, int ldb,
                                          int brow, int bcol, int K,
                                          int mode, _Float16* __restrict__ out0,
                                          _Float16* __restrict__ out1,
                                          int ldc, int zoff) {
    __shared__ _Float16 Asm[2][BM * BK];
    __shared__ _Float16 Bsm[2][BN * BK];
    constexpr int MR = BM / 32;
    constexpr int NC = BN / 32;
    constexpr int ABYTES = BM * BK * 2;
    constexpr int NLOAD = (BM + BN) * BK * 2 / 4096;
    static_assert(ABYTES % 4096 == 0, "A region must align to load passes");

    const int tid = threadIdx.x;
    const int lane = tid & 63;
    const int w = tid >> 6;
    const int wr = w >> 1, wc = w & 1;
    const int g = lane >> 4, r = lane & 15;

    f32x4 acc[MR][NC];
#pragma unroll
    for (int m = 0; m < MR; ++m)
#pragma unroll
        for (int n = 0; n < NC; ++n) acc[m][n] = (f32x4){0.f, 0.f, 0.f, 0.f};

    auto stage = [&](int buf, int kof) {
#pragma unroll
        for (int itl = 0; itl < NLOAD; ++itl) {
            int o = itl * 4096 + tid * 16;
            if (o < ABYTES) {
                int row = o >> 6, cb = o & 63;
                gload_lds16((const char*)(A + (size_t)(brow + row) * lda + kof) + cb,
                            (char*)Asm[buf] + o);
            } else {
                int o2 = o - ABYTES;
                int row = o2 >> 6, cb = o2 & 63;
                gload_lds16((const char*)(BT + (size_t)(bcol + row) * ldb + kof) + cb,
                            (char*)Bsm[buf] + o2);
            }
        }
    };

    stage(0, 0);
    __syncthreads();

    int cur = 0;
    const int nk = K / BK;
    for (int kt = 0; kt < nk; ++kt) {
        if (kt + 1 < nk) stage(cur ^ 1, (kt + 1) * BK);
        f16x8 af[MR], bf[NC];
#pragma unroll
        for (int m = 0; m < MR; ++m)
            af[m] = *(const f16x8*)&Asm[cur][((BM / 2) * wr + 16 * m + r) * BK + 8 * g];
#pragma unroll
        for (int n = 0; n < NC; ++n)
            bf[n] = *(const f16x8*)&Bsm[cur][((BN / 2) * wc + 16 * n + r) * BK + 8 * g];
#pragma unroll
        for (int m = 0; m < MR; ++m)
#pragma unroll
            for (int n = 0; n < NC; ++n)
                acc[m][n] = __builtin_amdgcn_mfma_f32_16x16x32_f16(af[m], bf[n], acc[m][n], 0, 0, 0);
        __syncthreads();
        cur ^= 1;
    }

    // epilogue: C/D layout col = lane&15, row = (lane>>4)*4 + reg   [m89-verified]
#pragma unroll
    for (int m = 0; m < MR; ++m)
#pragma unroll
        for (int n = 0; n < NC; ++n) {
            const int colg = bcol + (BN / 2) * wc + 16 * n + r;
            const int rowbase = brow + (BM / 2) * wr + 16 * m + 4 * g;
            if (mode == 0) {
#pragma unroll
                for (int r4 = 0; r4 < 4; ++r4)
                    out0[(size_t)(rowbase + r4) * ldc + colg] = (_Float16)acc[m][n][r4];
            } else if (mode == 1) {
                f16x4 pk = __builtin_convertvector(acc[m][n], f16x4);
                *(f16x4*)&out1[(size_t)colg * 2048 + rowbase] = pk;   // kT
                int hh = colg >> 6, dh = colg & 63;
#pragma unroll
                for (int r4 = 0; r4 < 4; ++r4) {
                    int kv = rowbase + r4;
                    int bb = kv >> 10, kvl = kv & 1023;
                    size_t flat = (((size_t)((bb * 16 + hh) * 64 + (kvl >> 4)) * 2 + (dh >> 5)) << 9)
                                  + (((kvl & 15) * 4 + ((dh >> 3) & 3)) << 3) + (dh & 7);
                    out0[flat] = pk[r4];
                }
            } else if (mode == 3) {
                int hh = rowbase >> 6, mpart_ = (rowbase >> 4) & 3;
                int bb = colg >> 10, kvl = colg & 1023;
#pragma unroll
                for (int r4 = 0; r4 < 4; ++r4) {
                    int dsub = (rowbase & 63) + r4;   // 16m+4g+r4
                    size_t flat = (((size_t)((((bb * 16 + hh) * 4 + mpart_) * 16 + (kvl >> 6)) * 2
                                             + ((kvl >> 5) & 1))) << 9)
                                  + (((dsub & 15) * 4 + ((kvl >> 3) & 3)) << 3) + (kvl & 7);
                    out0[flat] = (_Float16)acc[m][n][r4];
                }
            } else {   // mode 4: qfrag, pre-scaled
                int hh = colg >> 6, dh = colg & 63;
#pragma unroll
                for (int r4 = 0; r4 < 4; ++r4) {
                    int row = rowbase + r4;
                    size_t flat = (((size_t)((zoff * 16 + hh) * 64 + (row >> 4)) * 2 + (dh >> 5)) << 9)
                                  + (((row & 15) * 4 + ((dh >> 3) & 3)) << 3) + (dh & 7);
                    out0[flat] = (_Float16)(acc[m][n][r4] * SCALE2);
                }
            }
        }
}

// ---------------- fused QKV GEMM: 3 segments, 768 blocks ----------------
// seg0: qh           = xh @ Wq     (2048x1024 row-major)
// seg1: kfrag + kT   = yh @ Wk     (dual-layout write)
// seg2: vfrag        = WvT @ yh^T  (fragment layout)
__global__ __launch_bounds__(256) void gemm_qkv(const _Float16* __restrict__ xh,
                                                const _Float16* __restrict__ yh,
                                                const _Float16* __restrict__ WqT,
                                                const _Float16* __restrict__ WkT,
                                                const _Float16* __restrict__ WvT,
                                                _Float16* __restrict__ qh,
                                                _Float16* __restrict__ kfrag,
                                                _Float16* __restrict__ kT,
                                                _Float16* __restrict__ vfrag) {
    const int seg = blockIdx.x >> 8;
    const int t = blockIdx.x & 255;
    if (seg == 0)
        gemm_body<128, 64>(xh, WqT, 1024, 1024, (t >> 4) * 128, (t & 15) * 64, 1024,
                           0, qh, nullptr, 1024, 0);
    else if (seg == 1)
        gemm_body<128, 64>(yh, WkT, 1024, 1024, (t >> 4) * 128, (t & 15) * 64, 1024,
                           1, kfrag, kT, 0, 0);
    else
        gemm_body<128, 64>(WvT, yh, 1024, 1024, (t >> 5) * 128, (t & 31) * 64, 1024,
                           3, vfrag, nullptr, 0, 0);
}

// ---------------- batched QK GEMM: qfrag[b] = SCALE2 * (q[b] @ kflat[b]) in fragment layout ----------------
__global__ __launch_bounds__(256) void gemm_qk(const _Float16* __restrict__ qh,
                                               const _Float16* __restrict__ kT,
                                               _Float16* __restrict__ qfrag) {
    const int z = blockIdx.z;
    gemm_body<64, 64>(qh + (size_t)z * NN * ND, kT + z * NN, 1024, 2048,
                      blockIdx.y * 64, blockIdx.x * 64, 1024, 4, qfrag, nullptr, 0, z);
}

// ---------------- MFMA flash attention, operand-swapped, KV-split partials ----------------
// S^T = mfma(K, Q), O^T = mfma(V, P): lane r owns softmax row i=r entirely.
// Row reduce = in-lane f32x4 tree + 2 shfl_xor (g-groups). m/l are per-lane scalars.
__global__ __launch_bounds__(256) void flash_part(const _Float16* __restrict__ Qfrag,
                                                  const _Float16* __restrict__ Kfrag,
                                                  const _Float16* __restrict__ Vfrag,
                                                  _Float16* __restrict__ opart,
                                                  float* __restrict__ mpart,
                                                  float* __restrict__ lpart) {
    __shared__ _Float16 Ps[4][16][72];
    const int tid = threadIdx.x;
    const int lane = tid & 63;
    const int w = tid >> 6;
    const int g = lane >> 4, r = lane & 15;
    const int it = blockIdx.x;          // 0..15
    const int bh = blockIdx.y;          // 0..31 (= b*16+h)
    const int sp = blockIdx.z;          // 0..NSPLIT-1
    const int b = bh >> 4, h = bh & 15;

    const int ch8 = ((r << 2) + g) << 3;   // lane's chunk offset (f16) within a 1KB fragment block

    const _Float16* Qf = Qfrag + (((size_t)bh * 64 + it * 4 + w) << 10);
    const _Float16* Kf = Kfrag + ((size_t)bh << 16);
    const _Float16* Vf = Vfrag + ((size_t)bh << 16);

    // Q fragments (SCALE2 pre-folded at gemm_qk epilogue)
    f16x8 qa[2];
#pragma unroll
    for (int kk = 0; kk < 2; ++kk)
        qa[kk] = *(const f16x8*)&Qf[kk * 512 + ch8];

    float m_i = -1e30f, l_i = 0.f;
    f32x4 o[4];
#pragma unroll
    for (int n = 0; n < 4; ++n) o[n] = (f32x4){0.f, 0.f, 0.f, 0.f};

    for (int jt = sp * JPS; jt < sp * JPS + JPS; ++jt) {
        // ---- coalesced fragment loads: each a contiguous 1KB wave-read ----
        f16x8 kfr[4][2], vfr[4][2];
#pragma unroll
        for (int f = 0; f < 4; ++f)
#pragma unroll
            for (int kk = 0; kk < 2; ++kk)
                kfr[f][kk] = *(const f16x8*)&Kf[(jt * 4 + f) * 1024 + kk * 512 + ch8];
#pragma unroll
        for (int n = 0; n < 4; ++n)
#pragma unroll
            for (int kk = 0; kk < 2; ++kk)
                vfr[n][kk] = *(const f16x8*)&Vf[(n * 16 + jt) * 1024 + kk * 512 + ch8];

        // ---- S^T tile: sT[f][reg] = S[i = r][j = 16f + 4g + reg] ----
        f32x4 sT[4];
#pragma unroll
        for (int f = 0; f < 4; ++f) sT[f] = (f32x4){0.f, 0.f, 0.f, 0.f};
#pragma unroll
        for (int f = 0; f < 4; ++f)
#pragma unroll
            for (int kk = 0; kk < 2; ++kk)
                sT[f] = __builtin_amdgcn_mfma_f32_16x16x32_f16(kfr[f][kk], qa[kk], sT[f], 0, 0, 0);

        // ---- row max: in-lane tree + 2 cross-g shuffles ----
        f32x4 mm = vmax4(vmax4(sT[0], sT[1]), vmax4(sT[2], sT[3]));
        float mx = fmaxf(fmaxf(mm[0], mm[1]), fmaxf(mm[2], mm[3]));
        mx = fmaxf(mx, __shfl_xor(mx, 16));
        mx = fmaxf(mx, __shfl_xor(mx, 32));
        float mnew = fmaxf(m_i, mx);
        float corr = __expf(m_i - mnew);
        m_i = mnew;

        // ---- P = exp(S - m), row sum ----
        f32x4 p[4];
#pragma unroll
        for (int f = 0; f < 4; ++f)
#pragma unroll
            for (int reg = 0; reg < 4; ++reg)
                p[f][reg] = __expf(sT[f][reg] - mnew);
        f32x4 ps4 = (p[0] + p[1]) + (p[2] + p[3]);
        float rs = (ps4[0] + ps4[1]) + (ps4[2] + ps4[3]);
        rs += __shfl_xor(rs, 16);
        rs += __shfl_xor(rs, 32);
        l_i = l_i * corr + rs;

        // ---- P to wave-private LDS (packed 8B stores), rescale O ----
#pragma unroll
        for (int f = 0; f < 4; ++f)
            *(f16x4*)&Ps[w][r][16 * f + 4 * g] = __builtin_convertvector(p[f], f16x4);
#pragma unroll
        for (int n = 0; n < 4; ++n) o[n] *= corr;

        // ---- P B-fragments (lane r holds P-row r), lgkmcnt-ordered, no barrier ----
        f16x8 pa[2];
#pragma unroll
        for (int kk = 0; kk < 2; ++kk)
            pa[kk] = *(const f16x8*)&Ps[w][r][kk * 32 + 8 * g];

        // ---- O^T: o[n][reg] = O[i = r][dh = 16n + 4g + reg] ----
#pragma unroll
        for (int n = 0; n < 4; ++n)
#pragma unroll
            for (int kk = 0; kk < 2; ++kk)
                o[n] = __builtin_amdgcn_mfma_f32_16x16x32_f16(vfr[n][kk], pa[kk], o[n], 0, 0, 0);
    }

    // epilogue: unnormalized partial O (f16, packed 8B stores) + per-row m,l
    _Float16* Ob = opart + (size_t)sp * NB * NN * ND + ((size_t)b * NN + it * 64 + 16 * w) * ND + h * 64;
#pragma unroll
    for (int n = 0; n < 4; ++n)
        *(f16x4*)&Ob[(size_t)r * ND + 16 * n + 4 * g] = __builtin_convertvector(o[n], f16x4);

    if (lane < 16) {
        int base = (((sp * NB) + b) * NH + h) * NN + it * 64 + 16 * w + r;
        mpart[base] = m_i;
        lpart[base] = l_i;
    }
}

// ---------------- combine partials + residual + LayerNorm ----------------
__global__ __launch_bounds__(256) void ln_combine(const _Float16* __restrict__ opart,
                                                  const float* __restrict__ mpart,
                                                  const float* __restrict__ lpart,
                                                  const float* __restrict__ Y,
                                                  const float* __restrict__ gamma,
                                                  const float* __restrict__ beta,
                                                  float* __restrict__ Out) {
    const int row = blockIdx.x;   // b*NN + n
    const int b = row >> 10, n = row & 1023;
    const int t = threadIdx.x;
    const int c0 = t * 4;
    const int h = c0 >> 6;

    float ms[NSPLIT], ls[NSPLIT];
    float M = -1e30f;
#pragma unroll
    for (int s = 0; s < NSPLIT; ++s) {
        int idx = (((s * NB) + b) * NH + h) * NN + n;
        ms[s] = mpart[idx];
        ls[s] = lpart[idx];
        M = fmaxf(M, ms[s]);
    }
    float L = 0.f;
    float es[NSPLIT];
#pragma unroll
    for (int s = 0; s < NSPLIT; ++s) { es[s] = __expf(ms[s] - M); L += es[s] * ls[s]; }

    f32x4 acc = (f32x4){0.f, 0.f, 0.f, 0.f};
#pragma unroll
    for (int s = 0; s < NSPLIT; ++s) {
        f16x4 ov = *(const f16x4*)&opart[(size_t)s * NB * NN * ND + (size_t)row * ND + c0];
        acc += es[s] * __builtin_convertvector(ov, f32x4);
    }
    f32x4 z = acc * (1.0f / L) + *(const f32x4*)&Y[(size_t)row * ND + c0];

    __shared__ float red[8];
    float s1 = z.x + z.y + z.z + z.w;
#pragma unroll
    for (int off = 32; off; off >>= 1) s1 += __shfl_xor(s1, off);
    if ((t & 63) == 0) red[t >> 6] = s1;
    __syncthreads();
    float mean = (red[0] + red[1] + red[2] + red[3]) * (1.0f / 1024.0f);

    f32x4 d = z - mean;
    float sq = d.x * d.x + d.y * d.y + d.z * d.z + d.w * d.w;
#pragma unroll
    for (int off = 32; off; off >>= 1) sq += __shfl_xor(sq, off);
    if ((t & 63) == 0) red[4 + (t >> 6)] = sq;
    __syncthreads();
    float var = (red[4] + red[5] + red[6] + red[7]) * (1.0f / 1024.0f);
    float rstd = rsqrtf(var + LNEPS);

    f32x4 gg = *(const f32x4*)&gamma[c0];
    f32x4 bb = *(const f32x4*)&beta[c0];
    f32x4 res = d * rstd * gg + bb;
    *(f32x4*)&Out[(size_t)row * ND + c0] = res;
}

// ---------------- launch ----------------
extern "C" void kernel_launch(void* const* d_in, const int* in_sizes, int n_in,
                              void* d_out, int out_size, void* d_ws, size_t ws_size,
                              hipStream_t stream) {
    const float* x = (const float*)d_in[0];
    const float* y = (const float*)d_in[1];
    const float* Wq = (const float*)d_in[2];
    const float* Wk = (const float*)d_in[3];
    const float* Wv = (const float*)d_in[4];
    const float* gamma = (const float*)d_in[5];
    const float* beta = (const float*)d_in[6];
    float* out = (float*)d_out;

    const size_t MB = 1024ull * 1024ull;
    char* w = (char*)d_ws;
    _Float16* xh    = (_Float16*)(w + 0 * MB);    // 4 MB
    _Float16* yh    = (_Float16*)(w + 4 * MB);    // 4 MB
    _Float16* WqT   = (_Float16*)(w + 8 * MB);    // 2 MB
    _Float16* WkT   = (_Float16*)(w + 10 * MB);   // 2 MB
    _Float16* WvT   = (_Float16*)(w + 12 * MB);   // 2 MB
    _Float16* qh    = (_Float16*)(w + 14 * MB);   // 4 MB
    _Float16* kT    = (_Float16*)(w + 18 * MB);   // 4 MB  (k^T, ld 2048)
    _Float16* kfrag = (_Float16*)(w + 22 * MB);   // 4 MB  (K fragment layout)
    _Float16* vfrag = (_Float16*)(w + 26 * MB);   // 4 MB  (V fragment layout)
    _Float16* qfrag = (_Float16*)(w + 30 * MB);   // 4 MB  (Q' fragment layout, pre-scaled)
    _Float16* opart = (_Float16*)(w + 34 * MB);   // 16 MB (NSPLIT x 2048 x 1024 f16)
    float* mpart = (float*)(w + 50 * MB);         // 0.5 MB
    float* lpart = (float*)(w + 50 * MB + 512 * 1024);  // 0.5 MB  (total 51 MB)

    prep<<<5120, 256, 0, stream>>>(x, y, Wq, Wk, Wv, xh, yh, WqT, WkT, WvT);

    gemm_qkv<<<768, 256, 0, stream>>>(xh, yh, WqT, WkT, WvT, qh, kfrag, kT, vfrag);

    gemm_qk<<<dim3(16, 16, 2), 256, 0, stream>>>(qh, kT, qfrag);

    flash_part<<<dim3(16, 32, NSPLIT), 256, 0, stream>>>(qfrag, kfrag, vfrag, opart, mpart, lpart);

    ln_combine<<<NB * NN, 256, 0, stream>>>(opart, mpart, lpart, y, gamma, beta, out);
}